// Round 10
// baseline (426.385 us; speedup 1.0000x reference)
//
#include <hip/hip_runtime.h>

__device__ __forceinline__ float lrelu(float x) { return x >= 0.0f ? x : 0.2f * x; }

// Barrier without vmcnt drain: LDS-drain + s_barrier, memory-clobbered on both
// sides so LDS ops can't migrate across.
#define BAR()                                                \
  do {                                                       \
    asm volatile("s_waitcnt lgkmcnt(0)" ::: "memory");       \
    __builtin_amdgcn_s_barrier();                            \
    asm volatile("" ::: "memory");                           \
  } while (0)

#define PIN4(W) asm volatile("" : "+v"(W.x), "+v"(W.y), "+v"(W.z), "+v"(W.w))

// Load one float4 of weight (rows DB..DB+3, column GOFF+k0) and pin it.
// Round-8 lesson: keep per-thread weight footprint <= ~60 VGPRs; 156 VGPRs
// (39 quads) gets demoted by the allocator despite pinning (VGPR=104, +16µs).
#define LWQ(W, SRC, DB, GOFF)                                \
  do {                                                       \
    W.x = (SRC)[(DB + 0) * 300 + (GOFF) + k0];               \
    W.y = (SRC)[(DB + 1) * 300 + (GOFF) + k0];               \
    W.z = (SRC)[(DB + 2) * 300 + (GOFF) + k0];               \
    W.w = (SRC)[(DB + 3) * 300 + (GOFF) + k0];               \
    PIN4(W);                                                 \
  } while (0)

// 20-deep partial dot against 5 register quads, using preloaded h0..h4.
#define DOT20(OUT, W0, W1, W2, W3, W4)                       \
  do {                                                       \
    float a0 = h0.x*W0.x + h1.x*W1.x + h2.x*W2.x + h3.x*W3.x + h4.x*W4.x; \
    float a1 = h0.y*W0.y + h1.y*W1.y + h2.y*W2.y + h3.y*W3.y + h4.y*W4.y; \
    float a2 = h0.z*W0.z + h1.z*W1.z + h2.z*W2.z + h3.z*W3.z + h4.z*W4.z; \
    float a3 = h0.w*W0.w + h1.w*W1.w + h2.w*W2.w + h3.w*W3.w + h4.w*W4.w; \
    OUT = (a0 + a1) + (a2 + a3);                             \
  } while (0)

// ---------------- conv1: (256,160,160,2) -> (256,40,40,8), k7 s4 pad(1,2), +b, leaky, bn1
// Branchy tap loop. Round-7 lesson: full predication + unroll hoists ~98
// loads -> 256 VGPR + scratch spill (WRITE_SIZE 440MB). Keep branchy.
__global__ __launch_bounds__(256) void conv1_kernel(
    const float* __restrict__ in, const float* __restrict__ wt,
    const float* __restrict__ bias, const float* __restrict__ gamma,
    const float* __restrict__ beta, float* __restrict__ out) {
  __shared__ __align__(16) float w[784];   // [ky][kx][ic2][oc8]
  __shared__ float bb[8], sc[8], bt[8];
  for (int i = threadIdx.x; i < 784; i += 256) w[i] = wt[i];
  if (threadIdx.x < 8) {
    bb[threadIdx.x] = bias[threadIdx.x];
    sc[threadIdx.x] = gamma[threadIdx.x] * rsqrtf(1.001f);
    bt[threadIdx.x] = beta[threadIdx.x];
  }
  __syncthreads();
  int idx = blockIdx.x * 256 + threadIdx.x;      // n*1600 + oy*40 + ox
  int ox = idx % 40; int t = idx / 40; int oy = t % 40; int n = t / 40;
  float acc[8];
#pragma unroll
  for (int o = 0; o < 8; o++) acc[o] = bb[o];
  const float* inb = in + (size_t)n * (160 * 160 * 2);
#pragma unroll
  for (int ky = 0; ky < 7; ky++) {
    int iy = oy * 4 + ky - 1;
    if (iy < 0 || iy >= 160) continue;
#pragma unroll
    for (int kx = 0; kx < 7; kx++) {
      int ix = ox * 4 + kx - 1;
      if (ix < 0 || ix >= 160) continue;
      const float* ip = inb + (iy * 160 + ix) * 2;
      float v0 = ip[0], v1 = ip[1];
      const float4* wp4 = (const float4*)&w[(ky * 7 + kx) * 16];
      float4 wa = wp4[0], wb = wp4[1], wc = wp4[2], wd = wp4[3];
      acc[0] += v0 * wa.x + v1 * wc.x;
      acc[1] += v0 * wa.y + v1 * wc.y;
      acc[2] += v0 * wa.z + v1 * wc.z;
      acc[3] += v0 * wa.w + v1 * wc.w;
      acc[4] += v0 * wb.x + v1 * wd.x;
      acc[5] += v0 * wb.y + v1 * wd.y;
      acc[6] += v0 * wb.z + v1 * wd.z;
      acc[7] += v0 * wb.w + v1 * wd.w;
    }
  }
#pragma unroll
  for (int o = 0; o < 8; o++) { float a = lrelu(acc[o]); acc[o] = a * sc[o] + bt[o]; }
  float4* op = (float4*)(out + (size_t)idx * 8);
  op[0] = make_float4(acc[0], acc[1], acc[2], acc[3]);
  op[1] = make_float4(acc[4], acc[5], acc[6], acc[7]);
}

// ---------------- conv2: (256,40,40,8) -> (256,10,10,16), branchy
__global__ __launch_bounds__(256) void conv2_kernel(
    const float* __restrict__ in, const float* __restrict__ wt,
    const float* __restrict__ bias, const float* __restrict__ gamma,
    const float* __restrict__ beta, float* __restrict__ out) {
  __shared__ __align__(16) float w[6272];  // [ky][kx][ic8][oc16]
  __shared__ float bb[16], sc[16], bt[16];
  for (int i = threadIdx.x; i < 6272; i += 256) w[i] = wt[i];
  if (threadIdx.x < 16) {
    bb[threadIdx.x] = bias[threadIdx.x];
    sc[threadIdx.x] = gamma[threadIdx.x] * rsqrtf(1.001f);
    bt[threadIdx.x] = beta[threadIdx.x];
  }
  __syncthreads();
  int idx = blockIdx.x * 256 + threadIdx.x;      // ((n*100)+d)*16 + oc
  int oc = idx & 15; int r = idx >> 4; int d = r % 100; int n = r / 100;
  int oy = d / 10, ox = d % 10;
  float acc = bb[oc];
  const float* inb = in + (size_t)n * (40 * 40 * 8);
#pragma unroll
  for (int ky = 0; ky < 7; ky++) {
    int iy = oy * 4 + ky - 1;
    if (iy < 0 || iy >= 40) continue;
#pragma unroll
    for (int kx = 0; kx < 7; kx++) {
      int ix = ox * 4 + kx - 1;
      if (ix < 0 || ix >= 40) continue;
      const float4* ip = (const float4*)(inb + (iy * 40 + ix) * 8);
      float4 a = ip[0], b = ip[1];
      const float* wp = &w[(ky * 7 + kx) * 128 + oc];
      acc += a.x * wp[0]  + a.y * wp[16] + a.z * wp[32] + a.w * wp[48]
           + b.x * wp[64] + b.y * wp[80] + b.z * wp[96] + b.w * wp[112];
    }
  }
  float a = lrelu(acc);
  out[idx] = a * sc[oc] + bt[oc];
}

// ---------------- xproj: per c: (256x100)@(100x300)+bx -> [c][t][k]
__global__ __launch_bounds__(1024, 4) void xproj_kernel(
    const float* __restrict__ x2, const float* __restrict__ wx,
    const float* __restrict__ gb, float* __restrict__ xproj) {
  int c = blockIdx.x;      // 0..15
  int tg = blockIdx.y;     // 0..15, t0 = tg*16
  int tid = threadIdx.x;
  __shared__ __align__(16) float fr[100];
  __shared__ float pbuf[912];
  const float* wxc = wx + (size_t)c * 30000;
  bool isA0 = (tid < 300);
  bool isA1 = (tid >= 320 && tid < 620);
  bool isA2 = (tid >= 640 && tid < 940);
  int k0 = isA0 ? tid : (isA1 ? tid - 320 : tid - 640);
  float4 w0, w1, w2, w3, w4, w5, w6, w7, w8;
  if (isA0) {
    LWQ(w0, wxc, 0, 0);  LWQ(w1, wxc, 4, 0);  LWQ(w2, wxc, 8, 0);
    LWQ(w3, wxc, 12, 0); LWQ(w4, wxc, 16, 0); LWQ(w5, wxc, 20, 0);
    LWQ(w6, wxc, 24, 0); LWQ(w7, wxc, 28, 0); LWQ(w8, wxc, 32, 0);
  } else if (isA1) {
    LWQ(w0, wxc, 36, 0); LWQ(w1, wxc, 40, 0); LWQ(w2, wxc, 44, 0);
    LWQ(w3, wxc, 48, 0); LWQ(w4, wxc, 52, 0); LWQ(w5, wxc, 56, 0);
    LWQ(w6, wxc, 60, 0); LWQ(w7, wxc, 64, 0);
  } else if (isA2) {
    LWQ(w0, wxc, 68, 0); LWQ(w1, wxc, 72, 0); LWQ(w2, wxc, 76, 0);
    LWQ(w3, wxc, 80, 0); LWQ(w4, wxc, 84, 0); LWQ(w5, wxc, 88, 0);
    LWQ(w6, wxc, 92, 0); LWQ(w7, wxc, 96, 0);
  }
  float bx = isA0 ? gb[c * 600 + tid] : 0.0f;
  int t0 = tg * 16;
  float v = (tid < 100) ? x2[(size_t)(t0) * 1600 + tid * 16 + c] : 0.0f;
#define XDOT(OFF, W) do { float4 h4_ = *(const float4*)&fr[OFF]; \
    a0 += h4_.x*W.x; a1 += h4_.y*W.y; a2 += h4_.z*W.z; a3 += h4_.w*W.w; } while (0)
  for (int tt = 0; tt < 16; tt++) {
    int t = t0 + tt;
    if (tid < 100) fr[tid] = v;
    BAR();
    if (tid < 100 && tt < 15) v = x2[(size_t)(t + 1) * 1600 + tid * 16 + c];
    float a0 = 0.f, a1 = 0.f, a2 = 0.f, a3 = 0.f;
    if (isA0) {
      XDOT(0, w0);  XDOT(4, w1);  XDOT(8, w2);  XDOT(12, w3); XDOT(16, w4);
      XDOT(20, w5); XDOT(24, w6); XDOT(28, w7); XDOT(32, w8);
      pbuf[k0] = (a0 + a1) + (a2 + a3);
    } else if (isA1) {
      XDOT(36, w0); XDOT(40, w1); XDOT(44, w2); XDOT(48, w3);
      XDOT(52, w4); XDOT(56, w5); XDOT(60, w6); XDOT(64, w7);
      pbuf[300 + k0] = (a0 + a1) + (a2 + a3);
    } else if (isA2) {
      XDOT(68, w0); XDOT(72, w1); XDOT(76, w2); XDOT(80, w3);
      XDOT(84, w4); XDOT(88, w5); XDOT(92, w6); XDOT(96, w7);
      pbuf[600 + k0] = (a0 + a1) + (a2 + a3);
    }
    BAR();
    if (isA0) {
      float s = pbuf[tid] + pbuf[300 + tid] + pbuf[600 + tid] + bx;
      xproj[((size_t)c * 256 + t) * 300 + tid] = s;
    }
    BAR();
  }
#undef XDOT
}

// Stage one 16-step group (4800 floats = 1200 x 16B) of xproj into LDS.
// 512-thread version. LDS dest: wave-uniform base + lane*16B.
__device__ __forceinline__ void stage_chunk512(const float* __restrict__ gsrc,
                                               float* lds_dst, int tid) {
  int wave = tid >> 6;
#pragma unroll
  for (int r = 0; r < 2; r++) {
    const float* g = gsrc + (size_t)(r * 512 + tid) * 4;
    float* l = lds_dst + (r * 512 + wave * 64) * 4;
    __builtin_amdgcn_global_load_lds(
        (const __attribute__((address_space(1))) unsigned int*)g,
        (__attribute__((address_space(3))) unsigned int*)l, 16, 0, 0);
  }
  if (tid < 176) {
    const float* g = gsrc + (size_t)(1024 + tid) * 4;
    float* l = lds_dst + (1024 + wave * 64) * 4;
    __builtin_amdgcn_global_load_lds(
        (const __attribute__((address_space(1))) unsigned int*)g,
        (__attribute__((address_space(3))) unsigned int*)l, 16, 0, 0);
  }
}

// ---------------- GRU: chunked-parallel over t. Grid (16 c, 16 chunks).
// Round-6 512-thread structure, warm-up 32 (r9: absmax bit-identical).
__global__ __launch_bounds__(512, 2) void gru_kernel(
    const float* __restrict__ xproj, const float* __restrict__ wh,
    const float* __restrict__ gb, float* __restrict__ rnn) {
  int c = blockIdx.x;
  int chunk = blockIdx.y;
  int tid = threadIdx.x;
  __shared__ __align__(16) float h_lds[100];
  __shared__ float pbuf[1560];                    // [g*3+gt][104]
  __shared__ __align__(16) float xbuf[2][4800];   // 38.4 KB
  const float* whc = wh + (size_t)c * 30000;
  bool mv = (tid < 500);
  int g  = mv ? tid / 100 : 0;
  int k0 = tid - g * 100;
  int db = 20 * g;
  float4 z0, z1, z2, z3, z4, r0, r1, r2, r3, r4, q0, q1, q2, q3, q4;
  if (mv) {
    LWQ(z0, whc, db + 0, 0);   LWQ(z1, whc, db + 4, 0);   LWQ(z2, whc, db + 8, 0);
    LWQ(z3, whc, db + 12, 0);  LWQ(z4, whc, db + 16, 0);
    LWQ(r0, whc, db + 0, 100); LWQ(r1, whc, db + 4, 100); LWQ(r2, whc, db + 8, 100);
    LWQ(r3, whc, db + 12, 100);LWQ(r4, whc, db + 16, 100);
    LWQ(q0, whc, db + 0, 200); LWQ(q1, whc, db + 4, 200); LWQ(q2, whc, db + 8, 200);
    LWQ(q3, whc, db + 12, 200);LWQ(q4, whc, db + 16, 200);
  }
  float bzb = 0.f, brb = 0.f, bhb = 0.f, hprev = 0.f;
  if (tid < 100) {
    bzb = gb[c * 600 + 300 + tid];
    brb = gb[c * 600 + 400 + tid];
    bhb = gb[c * 600 + 500 + tid];
    h_lds[tid] = 0.0f;
  }
  int t0 = chunk * 16;                     // first output step
  int t_start = (t0 >= 32) ? t0 - 32 : 0;  // warm-up start (W=32)
  int ng = (t0 + 16 - t_start) >> 4;       // 16-step groups: 1..3
  const float* xp = xproj + (size_t)c * 76800 + (size_t)t_start * 300;

  stage_chunk512(xp, xbuf[0], tid);
  asm volatile("s_waitcnt vmcnt(0)" ::: "memory");
  BAR();

  int pb0 = g * 312 + k0;    // pbuf base for this thread's 3 partials
  int cur = 0;
  for (int g16 = 0; g16 < ng; g16++) {
    if (g16 + 1 < ng) stage_chunk512(xp + (size_t)(g16 + 1) * 4800, xbuf[cur ^ 1], tid);
    int tb = t_start + g16 * 16;
    for (int s = 0; s < 16; s++) {
      if (mv) {
        float4 h0 = *(const float4*)&h_lds[db];
        float4 h1 = *(const float4*)&h_lds[db + 4];
        float4 h2 = *(const float4*)&h_lds[db + 8];
        float4 h3 = *(const float4*)&h_lds[db + 12];
        float4 h4 = *(const float4*)&h_lds[db + 16];
        float pz, pr, ph;
        DOT20(pz, z0, z1, z2, z3, z4);
        DOT20(pr, r0, r1, r2, r3, r4);
        DOT20(ph, q0, q1, q2, q3, q4);
        pbuf[pb0]       = pz;
        pbuf[pb0 + 104] = pr;
        pbuf[pb0 + 208] = ph;
      }
      BAR();
      if (tid < 100) {
        const float* xr_ = &xbuf[cur][s * 300];
        float rz = ((pbuf[tid]       + pbuf[312 + tid]) + (pbuf[624 + tid] + pbuf[936 + tid])) + pbuf[1248 + tid] + bzb;
        float rr = ((pbuf[104 + tid] + pbuf[416 + tid]) + (pbuf[728 + tid] + pbuf[1040 + tid])) + pbuf[1352 + tid] + brb;
        float rh = ((pbuf[208 + tid] + pbuf[520 + tid]) + (pbuf[832 + tid] + pbuf[1144 + tid])) + pbuf[1456 + tid] + bhb;
        float z = 1.0f / (1.0f + __expf(-(xr_[tid] + rz)));
        float r = 1.0f / (1.0f + __expf(-(xr_[100 + tid] + rr)));
        float e = __expf(2.0f * (xr_[200 + tid] + r * rh));
        float hh = 1.0f - 2.0f / (e + 1.0f);     // tanh
        float hn = z * hprev + (1.0f - z) * hh;
        hprev = hn;
        h_lds[tid] = hn;
        int t = tb + s;
        if (t >= t0)
          rnn[((size_t)t * 100 + tid) * 16 + c] = hn;
      }
      BAR();
    }
    // group boundary: next xbuf fully loaded (and stores drained)
    asm volatile("s_waitcnt vmcnt(0)" ::: "memory");
    BAR();
    cur ^= 1;
  }
}

// ---------------- deconv1: (256,10,10,16) -> (256,40,40,8), s4 k7, exact <=2x2 taps
__global__ __launch_bounds__(256) void deconv1_kernel(
    const float* __restrict__ rnn, const float* __restrict__ wt,
    const float* __restrict__ bias, const float* __restrict__ gamma,
    const float* __restrict__ beta, float* __restrict__ out) {
  __shared__ __align__(16) float w[6272];   // [ky][kx][ic16][oc8]
  __shared__ float bb[8], sc[8], bt[8];
  for (int i = threadIdx.x; i < 6272; i += 256) w[i] = wt[i];
  if (threadIdx.x < 8) {
    bb[threadIdx.x] = bias[threadIdx.x];
    sc[threadIdx.x] = gamma[threadIdx.x] * rsqrtf(1.001f);
    bt[threadIdx.x] = beta[threadIdx.x];
  }
  __syncthreads();
  int idx = blockIdx.x * 256 + threadIdx.x;     // n*1600 + oy*40 + ox
  int ox = idx % 40; int t2 = idx / 40; int oy = t2 % 40; int n = t2 / 40;
  float acc[8];
#pragma unroll
  for (int o = 0; o < 8; o++) acc[o] = bb[o];
  int kyA = (5 - oy) & 3;     // ky ≡ 5-oy (mod 4) → py = oy+ky-5 ≡ 0 (mod 4)
  int kxA = (5 - ox) & 3;
  const float* rb = rnn + (size_t)n * 1600;
#pragma unroll
  for (int ia = 0; ia < 2; ia++) {
    int ky = kyA + 4 * ia;
    int py = oy + ky - 5;
    if (ky > 6 || (unsigned)py >= 40u) continue;
    int iy = py >> 2;
#pragma unroll
    for (int ib = 0; ib < 2; ib++) {
      int kx = kxA + 4 * ib;
      int px = ox + kx - 5;
      if (kx > 6 || (unsigned)px >= 40u) continue;
      int ix = px >> 2;
      const float4* ip = (const float4*)(rb + (iy * 10 + ix) * 16);
      float4 v0 = ip[0], v1 = ip[1], v2 = ip[2], v3 = ip[3];
      const float* wp = &w[(ky * 7 + kx) * 128];
      float xv[16] = {v0.x, v0.y, v0.z, v0.w, v1.x, v1.y, v1.z, v1.w,
                      v2.x, v2.y, v2.z, v2.w, v3.x, v3.y, v3.z, v3.w};
#pragma unroll
      for (int ic = 0; ic < 16; ic++) {
        const float4* wq = (const float4*)&wp[ic * 8];
        float4 wA = wq[0], wB = wq[1];
        acc[0] += xv[ic] * wA.x; acc[1] += xv[ic] * wA.y;
        acc[2] += xv[ic] * wA.z; acc[3] += xv[ic] * wA.w;
        acc[4] += xv[ic] * wB.x; acc[5] += xv[ic] * wB.y;
        acc[6] += xv[ic] * wB.z; acc[7] += xv[ic] * wB.w;
      }
    }
  }
#pragma unroll
  for (int o = 0; o < 8; o++) { float a = lrelu(acc[o]); acc[o] = a * sc[o] + bt[o]; }
  float4* op = (float4*)(out + (size_t)idx * 8);
  op[0] = make_float4(acc[0], acc[1], acc[2], acc[3]);
  op[1] = make_float4(acc[4], acc[5], acc[6], acc[7]);
}

// ---------------- deconv2: (256,40,40,8) -> (256,160,160,2), s4 k7.
// 4x4-OUTPUT-BLOCK form: one thread computes the aligned 4x4 output tile
// (oy=4Y+r, ox=4X+c). For such a tile the taps reduce to the 3x3 input-cell
// neighborhood {Y-1,Y,Y+1}x{X-1,X,X+1} and EVERY kernel tap (ky,kx) is used
// exactly once: ky->(input row, out row) = 0:(Y-1,1) 1:(Y-1,0) 2:(Y,3)
// 3:(Y,2) 4:(Y,1) 5:(Y,0) 6:(Y+1,3); same map for kx/cols. 18 predicated
// float4 loads + 784 FMA + 8 coalesced 16B stores per thread (was ~96 loads,
// 1 px/thread). Loads grouped per input row (6 max in flight) to avoid the
// round-7 hoist-spill mode.
__global__ __launch_bounds__(256) void deconv2_kernel(
    const float* __restrict__ y1, const float* __restrict__ wt,
    const float* __restrict__ bias, const float* __restrict__ gs,
    float* __restrict__ out) {
  __shared__ __align__(16) float w[784];    // [ky][kx][ic8][oc2]
  for (int i = threadIdx.x; i < 784; i += 256) w[i] = wt[i];
  __syncthreads();
  int idx = blockIdx.x * 256 + threadIdx.x;     // n*1600 + Y*40 + X
  int X = idx % 40; int t2 = idx / 40; int Y = t2 % 40; int n = t2 / 40;
  float b0 = bias[0], b1 = bias[1];
  float acc[4][4][2];
#pragma unroll
  for (int r = 0; r < 4; r++)
#pragma unroll
    for (int c = 0; c < 4; c++) { acc[r][c][0] = b0; acc[r][c][1] = b1; }
  const float* yb = y1 + (size_t)n * (40 * 40 * 8);
  const float4 z4 = make_float4(0.f, 0.f, 0.f, 0.f);
  // per-ky / per-kx maps (compile-time after unroll):
  //   tap k -> neighbor cell index D (0:-1, 1:0, 2:+1) and output row/col R
  const int DMAP[7] = {0, 0, 1, 1, 1, 1, 2};
  const int RMAP[7] = {1, 0, 3, 2, 1, 0, 3};
  // ky sets per input-row neighbor: dy=0 -> {0,1}; dy=1 -> {2,3,4,5}; dy=2 -> {6}
  const int KYS[3][4] = {{0, 1, -1, -1}, {2, 3, 4, 5}, {6, -1, -1, -1}};
#pragma unroll
  for (int dy = 0; dy < 3; dy++) {
    int iy = Y + dy - 1;
    bool rowv = (unsigned)iy < 40u;
    float ci[3][8];
#pragma unroll
    for (int dx = 0; dx < 3; dx++) {
      int ix = X + dx - 1;
      bool v = rowv && (unsigned)ix < 40u;
      const float4* p = (const float4*)(yb + (iy * 40 + ix) * 8);
      float4 u = v ? p[0] : z4;
      float4 q = v ? p[1] : z4;
      ci[dx][0] = u.x; ci[dx][1] = u.y; ci[dx][2] = u.z; ci[dx][3] = u.w;
      ci[dx][4] = q.x; ci[dx][5] = q.y; ci[dx][6] = q.z; ci[dx][7] = q.w;
    }
#pragma unroll
    for (int kk = 0; kk < 4; kk++) {
      int ky = KYS[dy][kk];
      if (ky < 0) continue;
      int r = RMAP[ky];
#pragma unroll
      for (int kx = 0; kx < 7; kx++) {
        int dxi = DMAP[kx];
        int c = RMAP[kx];
        const float* wp = &w[(ky * 7 + kx) * 16];
        float s0 = 0.f, s1 = 0.f;
#pragma unroll
        for (int ic = 0; ic < 8; ic++) {
          s0 += ci[dxi][ic] * wp[ic * 2];
          s1 += ci[dxi][ic] * wp[ic * 2 + 1];
        }
        acc[r][c][0] += s0;
        acc[r][c][1] += s1;
      }
    }
  }
  float g = gs[0];
  size_t ob = ((size_t)n * 160 + 4 * Y) * 160 + 4 * X;   // pixel index
#pragma unroll
  for (int r = 0; r < 4; r++) {
    float4 s0 = make_float4(g * lrelu(acc[r][0][0]), g * lrelu(acc[r][0][1]),
                            g * lrelu(acc[r][1][0]), g * lrelu(acc[r][1][1]));
    float4 s1 = make_float4(g * lrelu(acc[r][2][0]), g * lrelu(acc[r][2][1]),
                            g * lrelu(acc[r][3][0]), g * lrelu(acc[r][3][1]));
    float4* op = (float4*)(out + (ob + (size_t)r * 160) * 2);
    op[0] = s0;
    op[1] = s1;
  }
}

extern "C" void kernel_launch(void* const* d_in, const int* in_sizes, int n_in,
                              void* d_out, int out_size, void* d_ws, size_t ws_size,
                              hipStream_t stream) {
  const float* lo_res   = (const float*)d_in[0];
  const float* conv1_k  = (const float*)d_in[1];
  const float* conv1_b  = (const float*)d_in[2];
  const float* bn1_g    = (const float*)d_in[3];
  const float* bn1_b    = (const float*)d_in[4];
  const float* conv2_k  = (const float*)d_in[5];
  const float* conv2_b  = (const float*)d_in[6];
  const float* bn2_g    = (const float*)d_in[7];
  const float* bn2_b    = (const float*)d_in[8];
  const float* gru_wx   = (const float*)d_in[9];
  const float* gru_wh   = (const float*)d_in[10];
  const float* gru_b    = (const float*)d_in[11];
  const float* deconv1_k = (const float*)d_in[12];
  const float* deconv1_b = (const float*)d_in[13];
  const float* deconv2_k = (const float*)d_in[14];
  const float* deconv2_b = (const float*)d_in[15];
  const float* gscale   = (const float*)d_in[16];

  float* ws = (float*)d_ws;
  float* x1    = ws;                    // 3,276,800
  float* x2    = x1 + 3276800;          //   409,600
  float* xproj = x2 + 409600;           // 1,228,800
  float* rnn   = xproj + 1228800;       //   409,600
  float* y1    = rnn + 409600;          // 3,276,800

  conv1_kernel<<<1600, 256, 0, stream>>>(lo_res, conv1_k, conv1_b, bn1_g, bn1_b, x1);
  conv2_kernel<<<1600, 256, 0, stream>>>(x1, conv2_k, conv2_b, bn2_g, bn2_b, x2);
  xproj_kernel<<<dim3(16, 16), 1024, 0, stream>>>(x2, gru_wx, gru_b, xproj);
  gru_kernel<<<dim3(16, 16), 512, 0, stream>>>(xproj, gru_wh, gru_b, rnn);
  deconv1_kernel<<<1600, 256, 0, stream>>>(rnn, deconv1_k, deconv1_b, bn1_g, bn1_b, y1);
  deconv2_kernel<<<1600, 256, 0, stream>>>(y1, deconv2_k, deconv2_b, gscale, (float*)d_out);
}

// Round 11
// 404.800 us; speedup vs baseline: 1.0533x; 1.0533x over previous
//
#include <hip/hip_runtime.h>

__device__ __forceinline__ float lrelu(float x) { return x >= 0.0f ? x : 0.2f * x; }

// Barrier without vmcnt drain: LDS-drain + s_barrier, memory-clobbered on both
// sides so LDS ops can't migrate across.
#define BAR()                                                \
  do {                                                       \
    asm volatile("s_waitcnt lgkmcnt(0)" ::: "memory");       \
    __builtin_amdgcn_s_barrier();                            \
    asm volatile("" ::: "memory");                           \
  } while (0)

#define PIN4(W) asm volatile("" : "+v"(W.x), "+v"(W.y), "+v"(W.z), "+v"(W.w))

// Load one float4 of weight (rows DB..DB+3, column GOFF+k0) and pin it.
// Round-8 lesson: keep per-thread weight footprint <= ~60 VGPRs.
#define LWQ(W, SRC, DB, GOFF)                                \
  do {                                                       \
    W.x = (SRC)[(DB + 0) * 300 + (GOFF) + k0];               \
    W.y = (SRC)[(DB + 1) * 300 + (GOFF) + k0];               \
    W.z = (SRC)[(DB + 2) * 300 + (GOFF) + k0];               \
    W.w = (SRC)[(DB + 3) * 300 + (GOFF) + k0];               \
    PIN4(W);                                                 \
  } while (0)

// 20-deep partial dot against 5 register quads, using preloaded h0..h4.
#define DOT20(OUT, W0, W1, W2, W3, W4)                       \
  do {                                                       \
    float a0 = h0.x*W0.x + h1.x*W1.x + h2.x*W2.x + h3.x*W3.x + h4.x*W4.x; \
    float a1 = h0.y*W0.y + h1.y*W1.y + h2.y*W2.y + h3.y*W3.y + h4.y*W4.y; \
    float a2 = h0.z*W0.z + h1.z*W1.z + h2.z*W2.z + h3.z*W3.z + h4.z*W4.z; \
    float a3 = h0.w*W0.w + h1.w*W1.w + h2.w*W2.w + h3.w*W3.w + h4.w*W4.w; \
    OUT = (a0 + a1) + (a2 + a3);                             \
  } while (0)

// ---------------- conv1: (256,160,160,2) -> (256,40,40,8), k7 s4 pad(1,2), +b, leaky, bn1
// Branchy tap loop. Round-7 lesson: full predication + unroll hoists ~98
// loads -> 256 VGPR + scratch spill. Keep branchy.
__global__ __launch_bounds__(256) void conv1_kernel(
    const float* __restrict__ in, const float* __restrict__ wt,
    const float* __restrict__ bias, const float* __restrict__ gamma,
    const float* __restrict__ beta, float* __restrict__ out) {
  __shared__ __align__(16) float w[784];   // [ky][kx][ic2][oc8]
  __shared__ float bb[8], sc[8], bt[8];
  for (int i = threadIdx.x; i < 784; i += 256) w[i] = wt[i];
  if (threadIdx.x < 8) {
    bb[threadIdx.x] = bias[threadIdx.x];
    sc[threadIdx.x] = gamma[threadIdx.x] * rsqrtf(1.001f);
    bt[threadIdx.x] = beta[threadIdx.x];
  }
  __syncthreads();
  int idx = blockIdx.x * 256 + threadIdx.x;      // n*1600 + oy*40 + ox
  int ox = idx % 40; int t = idx / 40; int oy = t % 40; int n = t / 40;
  float acc[8];
#pragma unroll
  for (int o = 0; o < 8; o++) acc[o] = bb[o];
  const float* inb = in + (size_t)n * (160 * 160 * 2);
#pragma unroll
  for (int ky = 0; ky < 7; ky++) {
    int iy = oy * 4 + ky - 1;
    if (iy < 0 || iy >= 160) continue;
#pragma unroll
    for (int kx = 0; kx < 7; kx++) {
      int ix = ox * 4 + kx - 1;
      if (ix < 0 || ix >= 160) continue;
      const float* ip = inb + (iy * 160 + ix) * 2;
      float v0 = ip[0], v1 = ip[1];
      const float4* wp4 = (const float4*)&w[(ky * 7 + kx) * 16];
      float4 wa = wp4[0], wb = wp4[1], wc = wp4[2], wd = wp4[3];
      acc[0] += v0 * wa.x + v1 * wc.x;
      acc[1] += v0 * wa.y + v1 * wc.y;
      acc[2] += v0 * wa.z + v1 * wc.z;
      acc[3] += v0 * wa.w + v1 * wc.w;
      acc[4] += v0 * wb.x + v1 * wd.x;
      acc[5] += v0 * wb.y + v1 * wd.y;
      acc[6] += v0 * wb.z + v1 * wd.z;
      acc[7] += v0 * wb.w + v1 * wd.w;
    }
  }
#pragma unroll
  for (int o = 0; o < 8; o++) { float a = lrelu(acc[o]); acc[o] = a * sc[o] + bt[o]; }
  float4* op = (float4*)(out + (size_t)idx * 8);
  op[0] = make_float4(acc[0], acc[1], acc[2], acc[3]);
  op[1] = make_float4(acc[4], acc[5], acc[6], acc[7]);
}

// ---------------- conv2: (256,40,40,8) -> (256,10,10,16), branchy
__global__ __launch_bounds__(256) void conv2_kernel(
    const float* __restrict__ in, const float* __restrict__ wt,
    const float* __restrict__ bias, const float* __restrict__ gamma,
    const float* __restrict__ beta, float* __restrict__ out) {
  __shared__ __align__(16) float w[6272];  // [ky][kx][ic8][oc16]
  __shared__ float bb[16], sc[16], bt[16];
  for (int i = threadIdx.x; i < 6272; i += 256) w[i] = wt[i];
  if (threadIdx.x < 16) {
    bb[threadIdx.x] = bias[threadIdx.x];
    sc[threadIdx.x] = gamma[threadIdx.x] * rsqrtf(1.001f);
    bt[threadIdx.x] = beta[threadIdx.x];
  }
  __syncthreads();
  int idx = blockIdx.x * 256 + threadIdx.x;      // ((n*100)+d)*16 + oc
  int oc = idx & 15; int r = idx >> 4; int d = r % 100; int n = r / 100;
  int oy = d / 10, ox = d % 10;
  float acc = bb[oc];
  const float* inb = in + (size_t)n * (40 * 40 * 8);
#pragma unroll
  for (int ky = 0; ky < 7; ky++) {
    int iy = oy * 4 + ky - 1;
    if (iy < 0 || iy >= 40) continue;
#pragma unroll
    for (int kx = 0; kx < 7; kx++) {
      int ix = ox * 4 + kx - 1;
      if (ix < 0 || ix >= 40) continue;
      const float4* ip = (const float4*)(inb + (iy * 40 + ix) * 8);
      float4 a = ip[0], b = ip[1];
      const float* wp = &w[(ky * 7 + kx) * 128 + oc];
      acc += a.x * wp[0]  + a.y * wp[16] + a.z * wp[32] + a.w * wp[48]
           + b.x * wp[64] + b.y * wp[80] + b.z * wp[96] + b.w * wp[112];
    }
  }
  float a = lrelu(acc);
  out[idx] = a * sc[oc] + bt[oc];
}

// ---------------- xproj: per c: (256x100)@(100x300)+bx -> [c][t][k]
__global__ __launch_bounds__(1024, 4) void xproj_kernel(
    const float* __restrict__ x2, const float* __restrict__ wx,
    const float* __restrict__ gb, float* __restrict__ xproj) {
  int c = blockIdx.x;      // 0..15
  int tg = blockIdx.y;     // 0..15, t0 = tg*16
  int tid = threadIdx.x;
  __shared__ __align__(16) float fr[100];
  __shared__ float pbuf[912];
  const float* wxc = wx + (size_t)c * 30000;
  bool isA0 = (tid < 300);
  bool isA1 = (tid >= 320 && tid < 620);
  bool isA2 = (tid >= 640 && tid < 940);
  int k0 = isA0 ? tid : (isA1 ? tid - 320 : tid - 640);
  float4 w0, w1, w2, w3, w4, w5, w6, w7, w8;
  if (isA0) {
    LWQ(w0, wxc, 0, 0);  LWQ(w1, wxc, 4, 0);  LWQ(w2, wxc, 8, 0);
    LWQ(w3, wxc, 12, 0); LWQ(w4, wxc, 16, 0); LWQ(w5, wxc, 20, 0);
    LWQ(w6, wxc, 24, 0); LWQ(w7, wxc, 28, 0); LWQ(w8, wxc, 32, 0);
  } else if (isA1) {
    LWQ(w0, wxc, 36, 0); LWQ(w1, wxc, 40, 0); LWQ(w2, wxc, 44, 0);
    LWQ(w3, wxc, 48, 0); LWQ(w4, wxc, 52, 0); LWQ(w5, wxc, 56, 0);
    LWQ(w6, wxc, 60, 0); LWQ(w7, wxc, 64, 0);
  } else if (isA2) {
    LWQ(w0, wxc, 68, 0); LWQ(w1, wxc, 72, 0); LWQ(w2, wxc, 76, 0);
    LWQ(w3, wxc, 80, 0); LWQ(w4, wxc, 84, 0); LWQ(w5, wxc, 88, 0);
    LWQ(w6, wxc, 92, 0); LWQ(w7, wxc, 96, 0);
  }
  float bx = isA0 ? gb[c * 600 + tid] : 0.0f;
  int t0 = tg * 16;
  float v = (tid < 100) ? x2[(size_t)(t0) * 1600 + tid * 16 + c] : 0.0f;
#define XDOT(OFF, W) do { float4 h4_ = *(const float4*)&fr[OFF]; \
    a0 += h4_.x*W.x; a1 += h4_.y*W.y; a2 += h4_.z*W.z; a3 += h4_.w*W.w; } while (0)
  for (int tt = 0; tt < 16; tt++) {
    int t = t0 + tt;
    if (tid < 100) fr[tid] = v;
    BAR();
    if (tid < 100 && tt < 15) v = x2[(size_t)(t + 1) * 1600 + tid * 16 + c];
    float a0 = 0.f, a1 = 0.f, a2 = 0.f, a3 = 0.f;
    if (isA0) {
      XDOT(0, w0);  XDOT(4, w1);  XDOT(8, w2);  XDOT(12, w3); XDOT(16, w4);
      XDOT(20, w5); XDOT(24, w6); XDOT(28, w7); XDOT(32, w8);
      pbuf[k0] = (a0 + a1) + (a2 + a3);
    } else if (isA1) {
      XDOT(36, w0); XDOT(40, w1); XDOT(44, w2); XDOT(48, w3);
      XDOT(52, w4); XDOT(56, w5); XDOT(60, w6); XDOT(64, w7);
      pbuf[300 + k0] = (a0 + a1) + (a2 + a3);
    } else if (isA2) {
      XDOT(68, w0); XDOT(72, w1); XDOT(76, w2); XDOT(80, w3);
      XDOT(84, w4); XDOT(88, w5); XDOT(92, w6); XDOT(96, w7);
      pbuf[600 + k0] = (a0 + a1) + (a2 + a3);
    }
    BAR();
    if (isA0) {
      float s = pbuf[tid] + pbuf[300 + tid] + pbuf[600 + tid] + bx;
      xproj[((size_t)c * 256 + t) * 300 + tid] = s;
    }
    BAR();
  }
#undef XDOT
}

// Stage one 16-step group (4800 floats = 1200 x 16B) of xproj into LDS.
// 512-thread version. LDS dest: wave-uniform base + lane*16B.
__device__ __forceinline__ void stage_chunk512(const float* __restrict__ gsrc,
                                               float* lds_dst, int tid) {
  int wave = tid >> 6;
#pragma unroll
  for (int r = 0; r < 2; r++) {
    const float* g = gsrc + (size_t)(r * 512 + tid) * 4;
    float* l = lds_dst + (r * 512 + wave * 64) * 4;
    __builtin_amdgcn_global_load_lds(
        (const __attribute__((address_space(1))) unsigned int*)g,
        (__attribute__((address_space(3))) unsigned int*)l, 16, 0, 0);
  }
  if (tid < 176) {
    const float* g = gsrc + (size_t)(1024 + tid) * 4;
    float* l = lds_dst + (1024 + wave * 64) * 4;
    __builtin_amdgcn_global_load_lds(
        (const __attribute__((address_space(1))) unsigned int*)g,
        (__attribute__((address_space(3))) unsigned int*)l, 16, 0, 0);
  }
}

// ---------------- GRU: chunked-parallel over t. Grid (16 c, 16 chunks).
// Round-6 512-thread structure, warm-up 32 (r9: absmax bit-identical).
__global__ __launch_bounds__(512, 2) void gru_kernel(
    const float* __restrict__ xproj, const float* __restrict__ wh,
    const float* __restrict__ gb, float* __restrict__ rnn) {
  int c = blockIdx.x;
  int chunk = blockIdx.y;
  int tid = threadIdx.x;
  __shared__ __align__(16) float h_lds[100];
  __shared__ float pbuf[1560];                    // [g*3+gt][104]
  __shared__ __align__(16) float xbuf[2][4800];   // 38.4 KB
  const float* whc = wh + (size_t)c * 30000;
  bool mv = (tid < 500);
  int g  = mv ? tid / 100 : 0;
  int k0 = tid - g * 100;
  int db = 20 * g;
  float4 z0, z1, z2, z3, z4, r0, r1, r2, r3, r4, q0, q1, q2, q3, q4;
  if (mv) {
    LWQ(z0, whc, db + 0, 0);   LWQ(z1, whc, db + 4, 0);   LWQ(z2, whc, db + 8, 0);
    LWQ(z3, whc, db + 12, 0);  LWQ(z4, whc, db + 16, 0);
    LWQ(r0, whc, db + 0, 100); LWQ(r1, whc, db + 4, 100); LWQ(r2, whc, db + 8, 100);
    LWQ(r3, whc, db + 12, 100);LWQ(r4, whc, db + 16, 100);
    LWQ(q0, whc, db + 0, 200); LWQ(q1, whc, db + 4, 200); LWQ(q2, whc, db + 8, 200);
    LWQ(q3, whc, db + 12, 200);LWQ(q4, whc, db + 16, 200);
  }
  float bzb = 0.f, brb = 0.f, bhb = 0.f, hprev = 0.f;
  if (tid < 100) {
    bzb = gb[c * 600 + 300 + tid];
    brb = gb[c * 600 + 400 + tid];
    bhb = gb[c * 600 + 500 + tid];
    h_lds[tid] = 0.0f;
  }
  int t0 = chunk * 16;                     // first output step
  int t_start = (t0 >= 32) ? t0 - 32 : 0;  // warm-up start (W=32)
  int ng = (t0 + 16 - t_start) >> 4;       // 16-step groups: 1..3
  const float* xp = xproj + (size_t)c * 76800 + (size_t)t_start * 300;

  stage_chunk512(xp, xbuf[0], tid);
  asm volatile("s_waitcnt vmcnt(0)" ::: "memory");
  BAR();

  int pb0 = g * 312 + k0;    // pbuf base for this thread's 3 partials
  int cur = 0;
  for (int g16 = 0; g16 < ng; g16++) {
    if (g16 + 1 < ng) stage_chunk512(xp + (size_t)(g16 + 1) * 4800, xbuf[cur ^ 1], tid);
    int tb = t_start + g16 * 16;
    for (int s = 0; s < 16; s++) {
      if (mv) {
        float4 h0 = *(const float4*)&h_lds[db];
        float4 h1 = *(const float4*)&h_lds[db + 4];
        float4 h2 = *(const float4*)&h_lds[db + 8];
        float4 h3 = *(const float4*)&h_lds[db + 12];
        float4 h4 = *(const float4*)&h_lds[db + 16];
        float pz, pr, ph;
        DOT20(pz, z0, z1, z2, z3, z4);
        DOT20(pr, r0, r1, r2, r3, r4);
        DOT20(ph, q0, q1, q2, q3, q4);
        pbuf[pb0]       = pz;
        pbuf[pb0 + 104] = pr;
        pbuf[pb0 + 208] = ph;
      }
      BAR();
      if (tid < 100) {
        const float* xr_ = &xbuf[cur][s * 300];
        float rz = ((pbuf[tid]       + pbuf[312 + tid]) + (pbuf[624 + tid] + pbuf[936 + tid])) + pbuf[1248 + tid] + bzb;
        float rr = ((pbuf[104 + tid] + pbuf[416 + tid]) + (pbuf[728 + tid] + pbuf[1040 + tid])) + pbuf[1352 + tid] + brb;
        float rh = ((pbuf[208 + tid] + pbuf[520 + tid]) + (pbuf[832 + tid] + pbuf[1144 + tid])) + pbuf[1456 + tid] + bhb;
        float z = 1.0f / (1.0f + __expf(-(xr_[tid] + rz)));
        float r = 1.0f / (1.0f + __expf(-(xr_[100 + tid] + rr)));
        float e = __expf(2.0f * (xr_[200 + tid] + r * rh));
        float hh = 1.0f - 2.0f / (e + 1.0f);     // tanh
        float hn = z * hprev + (1.0f - z) * hh;
        hprev = hn;
        h_lds[tid] = hn;
        int t = tb + s;
        if (t >= t0)
          rnn[((size_t)t * 100 + tid) * 16 + c] = hn;
      }
      BAR();
    }
    // group boundary: next xbuf fully loaded (and stores drained)
    asm volatile("s_waitcnt vmcnt(0)" ::: "memory");
    BAR();
    cur ^= 1;
  }
}

// ---------------- deconv1: (256,10,10,16) -> (256,40,40,8), s4 k7, exact <=2x2 taps
__global__ __launch_bounds__(256) void deconv1_kernel(
    const float* __restrict__ rnn, const float* __restrict__ wt,
    const float* __restrict__ bias, const float* __restrict__ gamma,
    const float* __restrict__ beta, float* __restrict__ out) {
  __shared__ __align__(16) float w[6272];   // [ky][kx][ic16][oc8]
  __shared__ float bb[8], sc[8], bt[8];
  for (int i = threadIdx.x; i < 6272; i += 256) w[i] = wt[i];
  if (threadIdx.x < 8) {
    bb[threadIdx.x] = bias[threadIdx.x];
    sc[threadIdx.x] = gamma[threadIdx.x] * rsqrtf(1.001f);
    bt[threadIdx.x] = beta[threadIdx.x];
  }
  __syncthreads();
  int idx = blockIdx.x * 256 + threadIdx.x;     // n*1600 + oy*40 + ox
  int ox = idx % 40; int t2 = idx / 40; int oy = t2 % 40; int n = t2 / 40;
  float acc[8];
#pragma unroll
  for (int o = 0; o < 8; o++) acc[o] = bb[o];
  int kyA = (5 - oy) & 3;     // ky ≡ 5-oy (mod 4) → py = oy+ky-5 ≡ 0 (mod 4)
  int kxA = (5 - ox) & 3;
  const float* rb = rnn + (size_t)n * 1600;
#pragma unroll
  for (int ia = 0; ia < 2; ia++) {
    int ky = kyA + 4 * ia;
    int py = oy + ky - 5;
    if (ky > 6 || (unsigned)py >= 40u) continue;
    int iy = py >> 2;
#pragma unroll
    for (int ib = 0; ib < 2; ib++) {
      int kx = kxA + 4 * ib;
      int px = ox + kx - 5;
      if (kx > 6 || (unsigned)px >= 40u) continue;
      int ix = px >> 2;
      const float4* ip = (const float4*)(rb + (iy * 10 + ix) * 16);
      float4 v0 = ip[0], v1 = ip[1], v2 = ip[2], v3 = ip[3];
      const float* wp = &w[(ky * 7 + kx) * 128];
      float xv[16] = {v0.x, v0.y, v0.z, v0.w, v1.x, v1.y, v1.z, v1.w,
                      v2.x, v2.y, v2.z, v2.w, v3.x, v3.y, v3.z, v3.w};
#pragma unroll
      for (int ic = 0; ic < 16; ic++) {
        const float4* wq = (const float4*)&wp[ic * 8];
        float4 wA = wq[0], wB = wq[1];
        acc[0] += xv[ic] * wA.x; acc[1] += xv[ic] * wA.y;
        acc[2] += xv[ic] * wA.z; acc[3] += xv[ic] * wA.w;
        acc[4] += xv[ic] * wB.x; acc[5] += xv[ic] * wB.y;
        acc[6] += xv[ic] * wB.z; acc[7] += xv[ic] * wB.w;
      }
    }
  }
#pragma unroll
  for (int o = 0; o < 8; o++) { float a = lrelu(acc[o]); acc[o] = a * sc[o] + bt[o]; }
  float4* op = (float4*)(out + (size_t)idx * 8);
  op[0] = make_float4(acc[0], acc[1], acc[2], acc[3]);
  op[1] = make_float4(acc[4], acc[5], acc[6], acc[7]);
}

// ---------------- deconv2: (256,40,40,8) -> (256,160,160,2), s4 k7.
// 4x4-output-block, ALL indices literal (round-10 lesson: local lookup
// arrays -> scratch -> runtime-indexed acc/ci -> 525MB spill. Rule #20.)
// Verified tap map (oy=4Y+r: ky ≡ 1-r mod 4, iy = Y+(r+ky-5)/4):
//   ky: 0->(Y-1,r1) 1->(Y-1,r0) 2->(Y,r3) 3->(Y,r2) 4->(Y,r1) 5->(Y,r0) 6->(Y+1,r3)
//   kx: same map for columns.
#define D2TAP(KY, KX, R, C, CU, CQ)                                   \
  do {                                                                \
    const float* wp_ = &w[((KY) * 7 + (KX)) * 16];                    \
    float s0_ = CU.x * wp_[0] + CU.y * wp_[2] + CU.z * wp_[4] +       \
                CU.w * wp_[6] + CQ.x * wp_[8] + CQ.y * wp_[10] +      \
                CQ.z * wp_[12] + CQ.w * wp_[14];                      \
    float s1_ = CU.x * wp_[1] + CU.y * wp_[3] + CU.z * wp_[5] +       \
                CU.w * wp_[7] + CQ.x * wp_[9] + CQ.y * wp_[11] +      \
                CQ.z * wp_[13] + CQ.w * wp_[15];                      \
    acc[R][C][0] += s0_;                                              \
    acc[R][C][1] += s1_;                                              \
  } while (0)

// All 7 kx taps for one ky (literal KY, literal output row R):
#define D2ROW(KY, R)                                                  \
  do {                                                                \
    D2TAP(KY, 0, R, 1, u0, q0);                                       \
    D2TAP(KY, 1, R, 0, u0, q0);                                       \
    D2TAP(KY, 2, R, 3, u1, q1);                                       \
    D2TAP(KY, 3, R, 2, u1, q1);                                       \
    D2TAP(KY, 4, R, 1, u1, q1);                                       \
    D2TAP(KY, 5, R, 0, u1, q1);                                       \
    D2TAP(KY, 6, R, 3, u2, q2);                                       \
  } while (0)

__global__ __launch_bounds__(256) void deconv2_kernel(
    const float* __restrict__ y1, const float* __restrict__ wt,
    const float* __restrict__ bias, const float* __restrict__ gs,
    float* __restrict__ out) {
  __shared__ __align__(16) float w[784];    // [ky][kx][ic8][oc2]
  for (int i = threadIdx.x; i < 784; i += 256) w[i] = wt[i];
  __syncthreads();
  int idx = blockIdx.x * 256 + threadIdx.x;     // n*1600 + Y*40 + X
  int X = idx % 40; int t2 = idx / 40; int Y = t2 % 40; int n = t2 / 40;
  float b0 = bias[0], b1 = bias[1];
  float acc[4][4][2];    // only literal indices below -> stays in VGPRs
#pragma unroll
  for (int r = 0; r < 4; r++)
#pragma unroll
    for (int c = 0; c < 4; c++) { acc[r][c][0] = b0; acc[r][c][1] = b1; }
  const float* yb = y1 + (size_t)n * (40 * 40 * 8);
  const float4 z4 = make_float4(0.f, 0.f, 0.f, 0.f);
  float4 u0, q0, u1, q1, u2, q2;

#define D2LOADROW(IY)                                                 \
  do {                                                                \
    bool rv_ = (unsigned)(IY) < 40u;                                  \
    const float4* p0_ = (const float4*)(yb + ((IY) * 40 + (X - 1)) * 8); \
    const float4* p1_ = (const float4*)(yb + ((IY) * 40 + X) * 8);    \
    const float4* p2_ = (const float4*)(yb + ((IY) * 40 + (X + 1)) * 8); \
    bool v0_ = rv_ && (X - 1) >= 0;                                   \
    bool v2_ = rv_ && (X + 1) < 40;                                   \
    u0 = v0_ ? p0_[0] : z4;  q0 = v0_ ? p0_[1] : z4;                  \
    u1 = rv_ ? p1_[0] : z4;  q1 = rv_ ? p1_[1] : z4;                  \
    u2 = v2_ ? p2_[0] : z4;  q2 = v2_ ? p2_[1] : z4;                  \
  } while (0)

  // input row Y-1: ky 0,1
  D2LOADROW(Y - 1);
  D2ROW(0, 1);
  D2ROW(1, 0);
  // input row Y: ky 2,3,4,5
  D2LOADROW(Y);
  D2ROW(2, 3);
  D2ROW(3, 2);
  D2ROW(4, 1);
  D2ROW(5, 0);
  // input row Y+1: ky 6
  D2LOADROW(Y + 1);
  D2ROW(6, 3);

  float g = gs[0];
  size_t ob = ((size_t)n * 160 + 4 * Y) * 160 + 4 * X;   // pixel index
#pragma unroll
  for (int r = 0; r < 4; r++) {
    float4 s0 = make_float4(g * lrelu(acc[r][0][0]), g * lrelu(acc[r][0][1]),
                            g * lrelu(acc[r][1][0]), g * lrelu(acc[r][1][1]));
    float4 s1 = make_float4(g * lrelu(acc[r][2][0]), g * lrelu(acc[r][2][1]),
                            g * lrelu(acc[r][3][0]), g * lrelu(acc[r][3][1]));
    float4* op = (float4*)(out + (ob + (size_t)r * 160) * 2);
    op[0] = s0;
    op[1] = s1;
  }
#undef D2LOADROW
}

extern "C" void kernel_launch(void* const* d_in, const int* in_sizes, int n_in,
                              void* d_out, int out_size, void* d_ws, size_t ws_size,
                              hipStream_t stream) {
  const float* lo_res   = (const float*)d_in[0];
  const float* conv1_k  = (const float*)d_in[1];
  const float* conv1_b  = (const float*)d_in[2];
  const float* bn1_g    = (const float*)d_in[3];
  const float* bn1_b    = (const float*)d_in[4];
  const float* conv2_k  = (const float*)d_in[5];
  const float* conv2_b  = (const float*)d_in[6];
  const float* bn2_g    = (const float*)d_in[7];
  const float* bn2_b    = (const float*)d_in[8];
  const float* gru_wx   = (const float*)d_in[9];
  const float* gru_wh   = (const float*)d_in[10];
  const float* gru_b    = (const float*)d_in[11];
  const float* deconv1_k = (const float*)d_in[12];
  const float* deconv1_b = (const float*)d_in[13];
  const float* deconv2_k = (const float*)d_in[14];
  const float* deconv2_b = (const float*)d_in[15];
  const float* gscale   = (const float*)d_in[16];

  float* ws = (float*)d_ws;
  float* x1    = ws;                    // 3,276,800
  float* x2    = x1 + 3276800;          //   409,600
  float* xproj = x2 + 409600;           // 1,228,800
  float* rnn   = xproj + 1228800;       //   409,600
  float* y1    = rnn + 409600;          // 3,276,800

  conv1_kernel<<<1600, 256, 0, stream>>>(lo_res, conv1_k, conv1_b, bn1_g, bn1_b, x1);
  conv2_kernel<<<1600, 256, 0, stream>>>(x1, conv2_k, conv2_b, bn2_g, bn2_b, x2);
  xproj_kernel<<<dim3(16, 16), 1024, 0, stream>>>(x2, gru_wx, gru_b, xproj);
  gru_kernel<<<dim3(16, 16), 512, 0, stream>>>(xproj, gru_wh, gru_b, rnn);
  deconv1_kernel<<<1600, 256, 0, stream>>>(rnn, deconv1_k, deconv1_b, bn1_g, bn1_b, y1);
  deconv2_kernel<<<1600, 256, 0, stream>>>(y1, deconv2_k, deconv2_b, gscale, (float*)d_out);
}

// Round 12
// 201.778 us; speedup vs baseline: 2.1131x; 2.0062x over previous
//
#include <hip/hip_runtime.h>

__device__ __forceinline__ float lrelu(float x) { return x >= 0.0f ? x : 0.2f * x; }

// Barrier without vmcnt drain: LDS-drain + s_barrier, memory-clobbered on both
// sides so LDS ops can't migrate across.
#define BAR()                                                \
  do {                                                       \
    asm volatile("s_waitcnt lgkmcnt(0)" ::: "memory");       \
    __builtin_amdgcn_s_barrier();                            \
    asm volatile("" ::: "memory");                           \
  } while (0)

#define PIN4(W) asm volatile("" : "+v"(W.x), "+v"(W.y), "+v"(W.z), "+v"(W.w))

// Load one float4 of weight (rows DB..DB+3, column GOFF+k0) and pin it.
// Round-8 lesson: keep per-thread weight footprint <= ~60 VGPRs.
#define LWQ(W, SRC, DB, GOFF)                                \
  do {                                                       \
    W.x = (SRC)[(DB + 0) * 300 + (GOFF) + k0];               \
    W.y = (SRC)[(DB + 1) * 300 + (GOFF) + k0];               \
    W.z = (SRC)[(DB + 2) * 300 + (GOFF) + k0];               \
    W.w = (SRC)[(DB + 3) * 300 + (GOFF) + k0];               \
    PIN4(W);                                                 \
  } while (0)

// 20-deep partial dot against 5 register quads, using preloaded h0..h4.
#define DOT20(OUT, W0, W1, W2, W3, W4)                       \
  do {                                                       \
    float a0 = h0.x*W0.x + h1.x*W1.x + h2.x*W2.x + h3.x*W3.x + h4.x*W4.x; \
    float a1 = h0.y*W0.y + h1.y*W1.y + h2.y*W2.y + h3.y*W3.y + h4.y*W4.y; \
    float a2 = h0.z*W0.z + h1.z*W1.z + h2.z*W2.z + h3.z*W3.z + h4.z*W4.z; \
    float a3 = h0.w*W0.w + h1.w*W1.w + h2.w*W2.w + h3.w*W3.w + h4.w*W4.w; \
    OUT = (a0 + a1) + (a2 + a3);                             \
  } while (0)

// ---------------- conv1: (256,160,160,2) -> (256,40,40,8), k7 s4 pad(1,2), +b, leaky, bn1
// Branchy tap loop. Round-7 lesson: full predication + unroll hoists ~98
// loads -> 256 VGPR + scratch spill. Keep branchy.
__global__ __launch_bounds__(256) void conv1_kernel(
    const float* __restrict__ in, const float* __restrict__ wt,
    const float* __restrict__ bias, const float* __restrict__ gamma,
    const float* __restrict__ beta, float* __restrict__ out) {
  __shared__ __align__(16) float w[784];   // [ky][kx][ic2][oc8]
  __shared__ float bb[8], sc[8], bt[8];
  for (int i = threadIdx.x; i < 784; i += 256) w[i] = wt[i];
  if (threadIdx.x < 8) {
    bb[threadIdx.x] = bias[threadIdx.x];
    sc[threadIdx.x] = gamma[threadIdx.x] * rsqrtf(1.001f);
    bt[threadIdx.x] = beta[threadIdx.x];
  }
  __syncthreads();
  int idx = blockIdx.x * 256 + threadIdx.x;      // n*1600 + oy*40 + ox
  int ox = idx % 40; int t = idx / 40; int oy = t % 40; int n = t / 40;
  float acc[8];
#pragma unroll
  for (int o = 0; o < 8; o++) acc[o] = bb[o];
  const float* inb = in + (size_t)n * (160 * 160 * 2);
#pragma unroll
  for (int ky = 0; ky < 7; ky++) {
    int iy = oy * 4 + ky - 1;
    if (iy < 0 || iy >= 160) continue;
#pragma unroll
    for (int kx = 0; kx < 7; kx++) {
      int ix = ox * 4 + kx - 1;
      if (ix < 0 || ix >= 160) continue;
      const float* ip = inb + (iy * 160 + ix) * 2;
      float v0 = ip[0], v1 = ip[1];
      const float4* wp4 = (const float4*)&w[(ky * 7 + kx) * 16];
      float4 wa = wp4[0], wb = wp4[1], wc = wp4[2], wd = wp4[3];
      acc[0] += v0 * wa.x + v1 * wc.x;
      acc[1] += v0 * wa.y + v1 * wc.y;
      acc[2] += v0 * wa.z + v1 * wc.z;
      acc[3] += v0 * wa.w + v1 * wc.w;
      acc[4] += v0 * wb.x + v1 * wd.x;
      acc[5] += v0 * wb.y + v1 * wd.y;
      acc[6] += v0 * wb.z + v1 * wd.z;
      acc[7] += v0 * wb.w + v1 * wd.w;
    }
  }
#pragma unroll
  for (int o = 0; o < 8; o++) { float a = lrelu(acc[o]); acc[o] = a * sc[o] + bt[o]; }
  float4* op = (float4*)(out + (size_t)idx * 8);
  op[0] = make_float4(acc[0], acc[1], acc[2], acc[3]);
  op[1] = make_float4(acc[4], acc[5], acc[6], acc[7]);
}

// ---------------- conv2: (256,40,40,8) -> (256,10,10,16), branchy
__global__ __launch_bounds__(256) void conv2_kernel(
    const float* __restrict__ in, const float* __restrict__ wt,
    const float* __restrict__ bias, const float* __restrict__ gamma,
    const float* __restrict__ beta, float* __restrict__ out) {
  __shared__ __align__(16) float w[6272];  // [ky][kx][ic8][oc16]
  __shared__ float bb[16], sc[16], bt[16];
  for (int i = threadIdx.x; i < 6272; i += 256) w[i] = wt[i];
  if (threadIdx.x < 16) {
    bb[threadIdx.x] = bias[threadIdx.x];
    sc[threadIdx.x] = gamma[threadIdx.x] * rsqrtf(1.001f);
    bt[threadIdx.x] = beta[threadIdx.x];
  }
  __syncthreads();
  int idx = blockIdx.x * 256 + threadIdx.x;      // ((n*100)+d)*16 + oc
  int oc = idx & 15; int r = idx >> 4; int d = r % 100; int n = r / 100;
  int oy = d / 10, ox = d % 10;
  float acc = bb[oc];
  const float* inb = in + (size_t)n * (40 * 40 * 8);
#pragma unroll
  for (int ky = 0; ky < 7; ky++) {
    int iy = oy * 4 + ky - 1;
    if (iy < 0 || iy >= 40) continue;
#pragma unroll
    for (int kx = 0; kx < 7; kx++) {
      int ix = ox * 4 + kx - 1;
      if (ix < 0 || ix >= 40) continue;
      const float4* ip = (const float4*)(inb + (iy * 40 + ix) * 8);
      float4 a = ip[0], b = ip[1];
      const float* wp = &w[(ky * 7 + kx) * 128 + oc];
      acc += a.x * wp[0]  + a.y * wp[16] + a.z * wp[32] + a.w * wp[48]
           + b.x * wp[64] + b.y * wp[80] + b.z * wp[96] + b.w * wp[112];
    }
  }
  float a = lrelu(acc);
  out[idx] = a * sc[oc] + bt[oc];
}

// ---------------- xproj: per c: (256x100)@(100x300)+bx -> [c][t][k]
__global__ __launch_bounds__(1024, 4) void xproj_kernel(
    const float* __restrict__ x2, const float* __restrict__ wx,
    const float* __restrict__ gb, float* __restrict__ xproj) {
  int c = blockIdx.x;      // 0..15
  int tg = blockIdx.y;     // 0..15, t0 = tg*16
  int tid = threadIdx.x;
  __shared__ __align__(16) float fr[100];
  __shared__ float pbuf[912];
  const float* wxc = wx + (size_t)c * 30000;
  bool isA0 = (tid < 300);
  bool isA1 = (tid >= 320 && tid < 620);
  bool isA2 = (tid >= 640 && tid < 940);
  int k0 = isA0 ? tid : (isA1 ? tid - 320 : tid - 640);
  float4 w0, w1, w2, w3, w4, w5, w6, w7, w8;
  if (isA0) {
    LWQ(w0, wxc, 0, 0);  LWQ(w1, wxc, 4, 0);  LWQ(w2, wxc, 8, 0);
    LWQ(w3, wxc, 12, 0); LWQ(w4, wxc, 16, 0); LWQ(w5, wxc, 20, 0);
    LWQ(w6, wxc, 24, 0); LWQ(w7, wxc, 28, 0); LWQ(w8, wxc, 32, 0);
  } else if (isA1) {
    LWQ(w0, wxc, 36, 0); LWQ(w1, wxc, 40, 0); LWQ(w2, wxc, 44, 0);
    LWQ(w3, wxc, 48, 0); LWQ(w4, wxc, 52, 0); LWQ(w5, wxc, 56, 0);
    LWQ(w6, wxc, 60, 0); LWQ(w7, wxc, 64, 0);
  } else if (isA2) {
    LWQ(w0, wxc, 68, 0); LWQ(w1, wxc, 72, 0); LWQ(w2, wxc, 76, 0);
    LWQ(w3, wxc, 80, 0); LWQ(w4, wxc, 84, 0); LWQ(w5, wxc, 88, 0);
    LWQ(w6, wxc, 92, 0); LWQ(w7, wxc, 96, 0);
  }
  float bx = isA0 ? gb[c * 600 + tid] : 0.0f;
  int t0 = tg * 16;
  float v = (tid < 100) ? x2[(size_t)(t0) * 1600 + tid * 16 + c] : 0.0f;
#define XDOT(OFF, W) do { float4 h4_ = *(const float4*)&fr[OFF]; \
    a0 += h4_.x*W.x; a1 += h4_.y*W.y; a2 += h4_.z*W.z; a3 += h4_.w*W.w; } while (0)
  for (int tt = 0; tt < 16; tt++) {
    int t = t0 + tt;
    if (tid < 100) fr[tid] = v;
    BAR();
    if (tid < 100 && tt < 15) v = x2[(size_t)(t + 1) * 1600 + tid * 16 + c];
    float a0 = 0.f, a1 = 0.f, a2 = 0.f, a3 = 0.f;
    if (isA0) {
      XDOT(0, w0);  XDOT(4, w1);  XDOT(8, w2);  XDOT(12, w3); XDOT(16, w4);
      XDOT(20, w5); XDOT(24, w6); XDOT(28, w7); XDOT(32, w8);
      pbuf[k0] = (a0 + a1) + (a2 + a3);
    } else if (isA1) {
      XDOT(36, w0); XDOT(40, w1); XDOT(44, w2); XDOT(48, w3);
      XDOT(52, w4); XDOT(56, w5); XDOT(60, w6); XDOT(64, w7);
      pbuf[300 + k0] = (a0 + a1) + (a2 + a3);
    } else if (isA2) {
      XDOT(68, w0); XDOT(72, w1); XDOT(76, w2); XDOT(80, w3);
      XDOT(84, w4); XDOT(88, w5); XDOT(92, w6); XDOT(96, w7);
      pbuf[600 + k0] = (a0 + a1) + (a2 + a3);
    }
    BAR();
    if (isA0) {
      float s = pbuf[tid] + pbuf[300 + tid] + pbuf[600 + tid] + bx;
      xproj[((size_t)c * 256 + t) * 300 + tid] = s;
    }
    BAR();
  }
#undef XDOT
}

// Stage one 16-step group (4800 floats = 1200 x 16B) of xproj into LDS.
// 512-thread version. LDS dest: wave-uniform base + lane*16B.
__device__ __forceinline__ void stage_chunk512(const float* __restrict__ gsrc,
                                               float* lds_dst, int tid) {
  int wave = tid >> 6;
#pragma unroll
  for (int r = 0; r < 2; r++) {
    const float* g = gsrc + (size_t)(r * 512 + tid) * 4;
    float* l = lds_dst + (r * 512 + wave * 64) * 4;
    __builtin_amdgcn_global_load_lds(
        (const __attribute__((address_space(1))) unsigned int*)g,
        (__attribute__((address_space(3))) unsigned int*)l, 16, 0, 0);
  }
  if (tid < 176) {
    const float* g = gsrc + (size_t)(1024 + tid) * 4;
    float* l = lds_dst + (1024 + wave * 64) * 4;
    __builtin_amdgcn_global_load_lds(
        (const __attribute__((address_space(1))) unsigned int*)g,
        (__attribute__((address_space(3))) unsigned int*)l, 16, 0, 0);
  }
}

// ---------------- GRU: chunked-parallel over t. Grid (16 c, 16 chunks).
// Round-6 512-thread structure, warm-up 32 (r9: absmax bit-identical).
__global__ __launch_bounds__(512, 2) void gru_kernel(
    const float* __restrict__ xproj, const float* __restrict__ wh,
    const float* __restrict__ gb, float* __restrict__ rnn) {
  int c = blockIdx.x;
  int chunk = blockIdx.y;
  int tid = threadIdx.x;
  __shared__ __align__(16) float h_lds[100];
  __shared__ float pbuf[1560];                    // [g*3+gt][104]
  __shared__ __align__(16) float xbuf[2][4800];   // 38.4 KB
  const float* whc = wh + (size_t)c * 30000;
  bool mv = (tid < 500);
  int g  = mv ? tid / 100 : 0;
  int k0 = tid - g * 100;
  int db = 20 * g;
  float4 z0, z1, z2, z3, z4, r0, r1, r2, r3, r4, q0, q1, q2, q3, q4;
  if (mv) {
    LWQ(z0, whc, db + 0, 0);   LWQ(z1, whc, db + 4, 0);   LWQ(z2, whc, db + 8, 0);
    LWQ(z3, whc, db + 12, 0);  LWQ(z4, whc, db + 16, 0);
    LWQ(r0, whc, db + 0, 100); LWQ(r1, whc, db + 4, 100); LWQ(r2, whc, db + 8, 100);
    LWQ(r3, whc, db + 12, 100);LWQ(r4, whc, db + 16, 100);
    LWQ(q0, whc, db + 0, 200); LWQ(q1, whc, db + 4, 200); LWQ(q2, whc, db + 8, 200);
    LWQ(q3, whc, db + 12, 200);LWQ(q4, whc, db + 16, 200);
  }
  float bzb = 0.f, brb = 0.f, bhb = 0.f, hprev = 0.f;
  if (tid < 100) {
    bzb = gb[c * 600 + 300 + tid];
    brb = gb[c * 600 + 400 + tid];
    bhb = gb[c * 600 + 500 + tid];
    h_lds[tid] = 0.0f;
  }
  int t0 = chunk * 16;                     // first output step
  int t_start = (t0 >= 32) ? t0 - 32 : 0;  // warm-up start (W=32)
  int ng = (t0 + 16 - t_start) >> 4;       // 16-step groups: 1..3
  const float* xp = xproj + (size_t)c * 76800 + (size_t)t_start * 300;

  stage_chunk512(xp, xbuf[0], tid);
  asm volatile("s_waitcnt vmcnt(0)" ::: "memory");
  BAR();

  int pb0 = g * 312 + k0;    // pbuf base for this thread's 3 partials
  int cur = 0;
  for (int g16 = 0; g16 < ng; g16++) {
    if (g16 + 1 < ng) stage_chunk512(xp + (size_t)(g16 + 1) * 4800, xbuf[cur ^ 1], tid);
    int tb = t_start + g16 * 16;
    for (int s = 0; s < 16; s++) {
      if (mv) {
        float4 h0 = *(const float4*)&h_lds[db];
        float4 h1 = *(const float4*)&h_lds[db + 4];
        float4 h2 = *(const float4*)&h_lds[db + 8];
        float4 h3 = *(const float4*)&h_lds[db + 12];
        float4 h4 = *(const float4*)&h_lds[db + 16];
        float pz, pr, ph;
        DOT20(pz, z0, z1, z2, z3, z4);
        DOT20(pr, r0, r1, r2, r3, r4);
        DOT20(ph, q0, q1, q2, q3, q4);
        pbuf[pb0]       = pz;
        pbuf[pb0 + 104] = pr;
        pbuf[pb0 + 208] = ph;
      }
      BAR();
      if (tid < 100) {
        const float* xr_ = &xbuf[cur][s * 300];
        float rz = ((pbuf[tid]       + pbuf[312 + tid]) + (pbuf[624 + tid] + pbuf[936 + tid])) + pbuf[1248 + tid] + bzb;
        float rr = ((pbuf[104 + tid] + pbuf[416 + tid]) + (pbuf[728 + tid] + pbuf[1040 + tid])) + pbuf[1352 + tid] + brb;
        float rh = ((pbuf[208 + tid] + pbuf[520 + tid]) + (pbuf[832 + tid] + pbuf[1144 + tid])) + pbuf[1456 + tid] + bhb;
        float z = 1.0f / (1.0f + __expf(-(xr_[tid] + rz)));
        float r = 1.0f / (1.0f + __expf(-(xr_[100 + tid] + rr)));
        float e = __expf(2.0f * (xr_[200 + tid] + r * rh));
        float hh = 1.0f - 2.0f / (e + 1.0f);     // tanh
        float hn = z * hprev + (1.0f - z) * hh;
        hprev = hn;
        h_lds[tid] = hn;
        int t = tb + s;
        if (t >= t0)
          rnn[((size_t)t * 100 + tid) * 16 + c] = hn;
      }
      BAR();
    }
    // group boundary: next xbuf fully loaded (and stores drained)
    asm volatile("s_waitcnt vmcnt(0)" ::: "memory");
    BAR();
    cur ^= 1;
  }
}

// ---------------- deconv1: (256,10,10,16) -> (256,40,40,8), s4 k7, exact <=2x2 taps
__global__ __launch_bounds__(256) void deconv1_kernel(
    const float* __restrict__ rnn, const float* __restrict__ wt,
    const float* __restrict__ bias, const float* __restrict__ gamma,
    const float* __restrict__ beta, float* __restrict__ out) {
  __shared__ __align__(16) float w[6272];   // [ky][kx][ic16][oc8]
  __shared__ float bb[8], sc[8], bt[8];
  for (int i = threadIdx.x; i < 6272; i += 256) w[i] = wt[i];
  if (threadIdx.x < 8) {
    bb[threadIdx.x] = bias[threadIdx.x];
    sc[threadIdx.x] = gamma[threadIdx.x] * rsqrtf(1.001f);
    bt[threadIdx.x] = beta[threadIdx.x];
  }
  __syncthreads();
  int idx = blockIdx.x * 256 + threadIdx.x;     // n*1600 + oy*40 + ox
  int ox = idx % 40; int t2 = idx / 40; int oy = t2 % 40; int n = t2 / 40;
  float acc[8];
#pragma unroll
  for (int o = 0; o < 8; o++) acc[o] = bb[o];
  int kyA = (5 - oy) & 3;     // ky ≡ 5-oy (mod 4) → py = oy+ky-5 ≡ 0 (mod 4)
  int kxA = (5 - ox) & 3;
  const float* rb = rnn + (size_t)n * 1600;
#pragma unroll
  for (int ia = 0; ia < 2; ia++) {
    int ky = kyA + 4 * ia;
    int py = oy + ky - 5;
    if (ky > 6 || (unsigned)py >= 40u) continue;
    int iy = py >> 2;
#pragma unroll
    for (int ib = 0; ib < 2; ib++) {
      int kx = kxA + 4 * ib;
      int px = ox + kx - 5;
      if (kx > 6 || (unsigned)px >= 40u) continue;
      int ix = px >> 2;
      const float4* ip = (const float4*)(rb + (iy * 10 + ix) * 16);
      float4 v0 = ip[0], v1 = ip[1], v2 = ip[2], v3 = ip[3];
      const float* wp = &w[(ky * 7 + kx) * 128];
      float xv[16] = {v0.x, v0.y, v0.z, v0.w, v1.x, v1.y, v1.z, v1.w,
                      v2.x, v2.y, v2.z, v2.w, v3.x, v3.y, v3.z, v3.w};
#pragma unroll
      for (int ic = 0; ic < 16; ic++) {
        const float4* wq = (const float4*)&wp[ic * 8];
        float4 wA = wq[0], wB = wq[1];
        acc[0] += xv[ic] * wA.x; acc[1] += xv[ic] * wA.y;
        acc[2] += xv[ic] * wA.z; acc[3] += xv[ic] * wA.w;
        acc[4] += xv[ic] * wB.x; acc[5] += xv[ic] * wB.y;
        acc[6] += xv[ic] * wB.z; acc[7] += xv[ic] * wB.w;
      }
    }
  }
#pragma unroll
  for (int o = 0; o < 8; o++) { float a = lrelu(acc[o]); acc[o] = a * sc[o] + bt[o]; }
  float4* op = (float4*)(out + (size_t)idx * 8);
  op[0] = make_float4(acc[0], acc[1], acc[2], acc[3]);
  op[1] = make_float4(acc[4], acc[5], acc[6], acc[7]);
}

// ---------------- deconv2: (256,40,40,8) -> (256,160,160,2), s4 k7.
// 4x4-output-block. Round-11 lesson: even literal-indexed, 784 LDS weight
// reads in straight-line code get hoisted by the scheduler -> 256 VGPR +
// scratch. Fix: (a) NO LDS weights — read wt from GLOBAL with literal
// (ky,kx) offsets: address is wave-uniform -> compiler emits s_load on the
// scalar pipe (SGPRs, not VGPRs; zero DS traffic); (b) sched_barrier(0)
// after EVERY tap caps in-flight loads at ~16 scalars + 6 input quads.
// Tap map verified on HW (r10/r11 passed, absmax identical):
//   ky: 0->(Y-1,r1) 1->(Y-1,r0) 2->(Y,r3) 3->(Y,r2) 4->(Y,r1) 5->(Y,r0) 6->(Y+1,r3)
//   kx: same map for columns.
#define D2TAP(KY, KX, R, C, CU, CQ)                                   \
  do {                                                                \
    const float* wp_ = wt + ((KY) * 7 + (KX)) * 16;                   \
    float s0_ = CU.x * wp_[0] + CU.y * wp_[2] + CU.z * wp_[4] +       \
                CU.w * wp_[6] + CQ.x * wp_[8] + CQ.y * wp_[10] +      \
                CQ.z * wp_[12] + CQ.w * wp_[14];                      \
    float s1_ = CU.x * wp_[1] + CU.y * wp_[3] + CU.z * wp_[5] +       \
                CU.w * wp_[7] + CQ.x * wp_[9] + CQ.y * wp_[11] +      \
                CQ.z * wp_[13] + CQ.w * wp_[15];                      \
    acc[R][C][0] += s0_;                                              \
    acc[R][C][1] += s1_;                                              \
    __builtin_amdgcn_sched_barrier(0);                                \
  } while (0)

// All 7 kx taps for one ky (literal KY, literal output row R):
#define D2ROW(KY, R)                                                  \
  do {                                                                \
    D2TAP(KY, 0, R, 1, u0, q0);                                       \
    D2TAP(KY, 1, R, 0, u0, q0);                                       \
    D2TAP(KY, 2, R, 3, u1, q1);                                       \
    D2TAP(KY, 3, R, 2, u1, q1);                                       \
    D2TAP(KY, 4, R, 1, u1, q1);                                       \
    D2TAP(KY, 5, R, 0, u1, q1);                                       \
    D2TAP(KY, 6, R, 3, u2, q2);                                       \
  } while (0)

__global__ __launch_bounds__(256) void deconv2_kernel(
    const float* __restrict__ y1, const float* __restrict__ wt,
    const float* __restrict__ bias, const float* __restrict__ gs,
    float* __restrict__ out) {
  int idx = blockIdx.x * 256 + threadIdx.x;     // n*1600 + Y*40 + X
  int X = idx % 40; int t2 = idx / 40; int Y = t2 % 40; int n = t2 / 40;
  float b0 = bias[0], b1 = bias[1];
  float acc[4][4][2];    // literal indices only (rule #20)
#pragma unroll
  for (int r = 0; r < 4; r++)
#pragma unroll
    for (int c = 0; c < 4; c++) { acc[r][c][0] = b0; acc[r][c][1] = b1; }
  const float* yb = y1 + (size_t)n * (40 * 40 * 8);
  const float4 z4 = make_float4(0.f, 0.f, 0.f, 0.f);
  float4 u0, q0, u1, q1, u2, q2;

#define D2LOADROW(IY)                                                 \
  do {                                                                \
    u0 = z4; q0 = z4; u1 = z4; q1 = z4; u2 = z4; q2 = z4;             \
    if ((unsigned)(IY) < 40u) {                                       \
      const float* rp_ = yb + (IY) * 320;                             \
      if (X > 0) { const float4* p_ = (const float4*)(rp_ + (X - 1) * 8); \
                   u0 = p_[0]; q0 = p_[1]; }                          \
      { const float4* p_ = (const float4*)(rp_ + X * 8);              \
        u1 = p_[0]; q1 = p_[1]; }                                     \
      if (X < 39) { const float4* p_ = (const float4*)(rp_ + (X + 1) * 8); \
                    u2 = p_[0]; q2 = p_[1]; }                         \
    }                                                                 \
    __builtin_amdgcn_sched_barrier(0);                                \
  } while (0)

  // input row Y-1: ky 0,1
  D2LOADROW(Y - 1);
  D2ROW(0, 1);
  D2ROW(1, 0);
  // input row Y: ky 2,3,4,5
  D2LOADROW(Y);
  D2ROW(2, 3);
  D2ROW(3, 2);
  D2ROW(4, 1);
  D2ROW(5, 0);
  // input row Y+1: ky 6
  D2LOADROW(Y + 1);
  D2ROW(6, 3);

  float g = gs[0];
  size_t ob = ((size_t)n * 160 + 4 * Y) * 160 + 4 * X;   // pixel index
#pragma unroll
  for (int r = 0; r < 4; r++) {
    float4 s0 = make_float4(g * lrelu(acc[r][0][0]), g * lrelu(acc[r][0][1]),
                            g * lrelu(acc[r][1][0]), g * lrelu(acc[r][1][1]));
    float4 s1 = make_float4(g * lrelu(acc[r][2][0]), g * lrelu(acc[r][2][1]),
                            g * lrelu(acc[r][3][0]), g * lrelu(acc[r][3][1]));
    float4* op = (float4*)(out + (ob + (size_t)r * 160) * 2);
    op[0] = s0;
    op[1] = s1;
  }
#undef D2LOADROW
}

extern "C" void kernel_launch(void* const* d_in, const int* in_sizes, int n_in,
                              void* d_out, int out_size, void* d_ws, size_t ws_size,
                              hipStream_t stream) {
  const float* lo_res   = (const float*)d_in[0];
  const float* conv1_k  = (const float*)d_in[1];
  const float* conv1_b  = (const float*)d_in[2];
  const float* bn1_g    = (const float*)d_in[3];
  const float* bn1_b    = (const float*)d_in[4];
  const float* conv2_k  = (const float*)d_in[5];
  const float* conv2_b  = (const float*)d_in[6];
  const float* bn2_g    = (const float*)d_in[7];
  const float* bn2_b    = (const float*)d_in[8];
  const float* gru_wx   = (const float*)d_in[9];
  const float* gru_wh   = (const float*)d_in[10];
  const float* gru_b    = (const float*)d_in[11];
  const float* deconv1_k = (const float*)d_in[12];
  const float* deconv1_b = (const float*)d_in[13];
  const float* deconv2_k = (const float*)d_in[14];
  const float* deconv2_b = (const float*)d_in[15];
  const float* gscale   = (const float*)d_in[16];

  float* ws = (float*)d_ws;
  float* x1    = ws;                    // 3,276,800
  float* x2    = x1 + 3276800;          //   409,600
  float* xproj = x2 + 409600;           // 1,228,800
  float* rnn   = xproj + 1228800;       //   409,600
  float* y1    = rnn + 409600;          // 3,276,800

  conv1_kernel<<<1600, 256, 0, stream>>>(lo_res, conv1_k, conv1_b, bn1_g, bn1_b, x1);
  conv2_kernel<<<1600, 256, 0, stream>>>(x1, conv2_k, conv2_b, bn2_g, bn2_b, x2);
  xproj_kernel<<<dim3(16, 16), 1024, 0, stream>>>(x2, gru_wx, gru_b, xproj);
  gru_kernel<<<dim3(16, 16), 512, 0, stream>>>(xproj, gru_wh, gru_b, rnn);
  deconv1_kernel<<<1600, 256, 0, stream>>>(rnn, deconv1_k, deconv1_b, bn1_g, bn1_b, y1);
  deconv2_kernel<<<1600, 256, 0, stream>>>(y1, deconv2_k, deconv2_b, gscale, (float*)d_out);
}

// Round 13
// 200.409 us; speedup vs baseline: 2.1276x; 1.0068x over previous
//
#include <hip/hip_runtime.h>

__device__ __forceinline__ float lrelu(float x) { return x >= 0.0f ? x : 0.2f * x; }

// Barrier without vmcnt drain: LDS-drain + s_barrier, memory-clobbered on both
// sides so LDS ops can't migrate across.
#define BAR()                                                \
  do {                                                       \
    asm volatile("s_waitcnt lgkmcnt(0)" ::: "memory");       \
    __builtin_amdgcn_s_barrier();                            \
    asm volatile("" ::: "memory");                           \
  } while (0)

#define PIN4(W) asm volatile("" : "+v"(W.x), "+v"(W.y), "+v"(W.z), "+v"(W.w))

// Load one float4 of weight (rows DB..DB+3, column GOFF+k0) and pin it.
// Round-8 lesson: keep per-thread weight footprint <= ~60 VGPRs.
#define LWQ(W, SRC, DB, GOFF)                                \
  do {                                                       \
    W.x = (SRC)[(DB + 0) * 300 + (GOFF) + k0];               \
    W.y = (SRC)[(DB + 1) * 300 + (GOFF) + k0];               \
    W.z = (SRC)[(DB + 2) * 300 + (GOFF) + k0];               \
    W.w = (SRC)[(DB + 3) * 300 + (GOFF) + k0];               \
    PIN4(W);                                                 \
  } while (0)

// 20-deep partial dot against 5 register quads, using preloaded h0..h4.
#define DOT20(OUT, W0, W1, W2, W3, W4)                       \
  do {                                                       \
    float a0 = h0.x*W0.x + h1.x*W1.x + h2.x*W2.x + h3.x*W3.x + h4.x*W4.x; \
    float a1 = h0.y*W0.y + h1.y*W1.y + h2.y*W2.y + h3.y*W3.y + h4.y*W4.y; \
    float a2 = h0.z*W0.z + h1.z*W1.z + h2.z*W2.z + h3.z*W3.z + h4.z*W4.z; \
    float a3 = h0.w*W0.w + h1.w*W1.w + h2.w*W2.w + h3.w*W3.w + h4.w*W4.w; \
    OUT = (a0 + a1) + (a2 + a3);                             \
  } while (0)

// ---------------- conv1: (256,160,160,2) -> (256,40,40,8), k7 s4 pad(1,2), +b, leaky, bn1
// Branchy tap loop. Round-7 lesson: full predication + unroll hoists ~98
// loads -> 256 VGPR + scratch spill. Keep branchy.
__global__ __launch_bounds__(256) void conv1_kernel(
    const float* __restrict__ in, const float* __restrict__ wt,
    const float* __restrict__ bias, const float* __restrict__ gamma,
    const float* __restrict__ beta, float* __restrict__ out) {
  __shared__ __align__(16) float w[784];   // [ky][kx][ic2][oc8]
  __shared__ float bb[8], sc[8], bt[8];
  for (int i = threadIdx.x; i < 784; i += 256) w[i] = wt[i];
  if (threadIdx.x < 8) {
    bb[threadIdx.x] = bias[threadIdx.x];
    sc[threadIdx.x] = gamma[threadIdx.x] * rsqrtf(1.001f);
    bt[threadIdx.x] = beta[threadIdx.x];
  }
  __syncthreads();
  int idx = blockIdx.x * 256 + threadIdx.x;      // n*1600 + oy*40 + ox
  int ox = idx % 40; int t = idx / 40; int oy = t % 40; int n = t / 40;
  float acc[8];
#pragma unroll
  for (int o = 0; o < 8; o++) acc[o] = bb[o];
  const float* inb = in + (size_t)n * (160 * 160 * 2);
#pragma unroll
  for (int ky = 0; ky < 7; ky++) {
    int iy = oy * 4 + ky - 1;
    if (iy < 0 || iy >= 160) continue;
#pragma unroll
    for (int kx = 0; kx < 7; kx++) {
      int ix = ox * 4 + kx - 1;
      if (ix < 0 || ix >= 160) continue;
      const float* ip = inb + (iy * 160 + ix) * 2;
      float v0 = ip[0], v1 = ip[1];
      const float4* wp4 = (const float4*)&w[(ky * 7 + kx) * 16];
      float4 wa = wp4[0], wb = wp4[1], wc = wp4[2], wd = wp4[3];
      acc[0] += v0 * wa.x + v1 * wc.x;
      acc[1] += v0 * wa.y + v1 * wc.y;
      acc[2] += v0 * wa.z + v1 * wc.z;
      acc[3] += v0 * wa.w + v1 * wc.w;
      acc[4] += v0 * wb.x + v1 * wd.x;
      acc[5] += v0 * wb.y + v1 * wd.y;
      acc[6] += v0 * wb.z + v1 * wd.z;
      acc[7] += v0 * wb.w + v1 * wd.w;
    }
  }
#pragma unroll
  for (int o = 0; o < 8; o++) { float a = lrelu(acc[o]); acc[o] = a * sc[o] + bt[o]; }
  float4* op = (float4*)(out + (size_t)idx * 8);
  op[0] = make_float4(acc[0], acc[1], acc[2], acc[3]);
  op[1] = make_float4(acc[4], acc[5], acc[6], acc[7]);
}

// ---------------- conv2: (256,40,40,8) -> (256,10,10,16), branchy
__global__ __launch_bounds__(256) void conv2_kernel(
    const float* __restrict__ in, const float* __restrict__ wt,
    const float* __restrict__ bias, const float* __restrict__ gamma,
    const float* __restrict__ beta, float* __restrict__ out) {
  __shared__ __align__(16) float w[6272];  // [ky][kx][ic8][oc16]
  __shared__ float bb[16], sc[16], bt[16];
  for (int i = threadIdx.x; i < 6272; i += 256) w[i] = wt[i];
  if (threadIdx.x < 16) {
    bb[threadIdx.x] = bias[threadIdx.x];
    sc[threadIdx.x] = gamma[threadIdx.x] * rsqrtf(1.001f);
    bt[threadIdx.x] = beta[threadIdx.x];
  }
  __syncthreads();
  int idx = blockIdx.x * 256 + threadIdx.x;      // ((n*100)+d)*16 + oc
  int oc = idx & 15; int r = idx >> 4; int d = r % 100; int n = r / 100;
  int oy = d / 10, ox = d % 10;
  float acc = bb[oc];
  const float* inb = in + (size_t)n * (40 * 40 * 8);
#pragma unroll
  for (int ky = 0; ky < 7; ky++) {
    int iy = oy * 4 + ky - 1;
    if (iy < 0 || iy >= 40) continue;
#pragma unroll
    for (int kx = 0; kx < 7; kx++) {
      int ix = ox * 4 + kx - 1;
      if (ix < 0 || ix >= 40) continue;
      const float4* ip = (const float4*)(inb + (iy * 40 + ix) * 8);
      float4 a = ip[0], b = ip[1];
      const float* wp = &w[(ky * 7 + kx) * 128 + oc];
      acc += a.x * wp[0]  + a.y * wp[16] + a.z * wp[32] + a.w * wp[48]
           + b.x * wp[64] + b.y * wp[80] + b.z * wp[96] + b.w * wp[112];
    }
  }
  float a = lrelu(acc);
  out[idx] = a * sc[oc] + bt[oc];
}

// ---------------- xproj: per c: (256x100)@(100x300)+bx -> [c][t][k]
__global__ __launch_bounds__(1024, 4) void xproj_kernel(
    const float* __restrict__ x2, const float* __restrict__ wx,
    const float* __restrict__ gb, float* __restrict__ xproj) {
  int c = blockIdx.x;      // 0..15
  int tg = blockIdx.y;     // 0..15, t0 = tg*16
  int tid = threadIdx.x;
  __shared__ __align__(16) float fr[100];
  __shared__ float pbuf[912];
  const float* wxc = wx + (size_t)c * 30000;
  bool isA0 = (tid < 300);
  bool isA1 = (tid >= 320 && tid < 620);
  bool isA2 = (tid >= 640 && tid < 940);
  int k0 = isA0 ? tid : (isA1 ? tid - 320 : tid - 640);
  float4 w0, w1, w2, w3, w4, w5, w6, w7, w8;
  if (isA0) {
    LWQ(w0, wxc, 0, 0);  LWQ(w1, wxc, 4, 0);  LWQ(w2, wxc, 8, 0);
    LWQ(w3, wxc, 12, 0); LWQ(w4, wxc, 16, 0); LWQ(w5, wxc, 20, 0);
    LWQ(w6, wxc, 24, 0); LWQ(w7, wxc, 28, 0); LWQ(w8, wxc, 32, 0);
  } else if (isA1) {
    LWQ(w0, wxc, 36, 0); LWQ(w1, wxc, 40, 0); LWQ(w2, wxc, 44, 0);
    LWQ(w3, wxc, 48, 0); LWQ(w4, wxc, 52, 0); LWQ(w5, wxc, 56, 0);
    LWQ(w6, wxc, 60, 0); LWQ(w7, wxc, 64, 0);
  } else if (isA2) {
    LWQ(w0, wxc, 68, 0); LWQ(w1, wxc, 72, 0); LWQ(w2, wxc, 76, 0);
    LWQ(w3, wxc, 80, 0); LWQ(w4, wxc, 84, 0); LWQ(w5, wxc, 88, 0);
    LWQ(w6, wxc, 92, 0); LWQ(w7, wxc, 96, 0);
  }
  float bx = isA0 ? gb[c * 600 + tid] : 0.0f;
  int t0 = tg * 16;
  float v = (tid < 100) ? x2[(size_t)(t0) * 1600 + tid * 16 + c] : 0.0f;
#define XDOT(OFF, W) do { float4 h4_ = *(const float4*)&fr[OFF]; \
    a0 += h4_.x*W.x; a1 += h4_.y*W.y; a2 += h4_.z*W.z; a3 += h4_.w*W.w; } while (0)
  for (int tt = 0; tt < 16; tt++) {
    int t = t0 + tt;
    if (tid < 100) fr[tid] = v;
    BAR();
    if (tid < 100 && tt < 15) v = x2[(size_t)(t + 1) * 1600 + tid * 16 + c];
    float a0 = 0.f, a1 = 0.f, a2 = 0.f, a3 = 0.f;
    if (isA0) {
      XDOT(0, w0);  XDOT(4, w1);  XDOT(8, w2);  XDOT(12, w3); XDOT(16, w4);
      XDOT(20, w5); XDOT(24, w6); XDOT(28, w7); XDOT(32, w8);
      pbuf[k0] = (a0 + a1) + (a2 + a3);
    } else if (isA1) {
      XDOT(36, w0); XDOT(40, w1); XDOT(44, w2); XDOT(48, w3);
      XDOT(52, w4); XDOT(56, w5); XDOT(60, w6); XDOT(64, w7);
      pbuf[300 + k0] = (a0 + a1) + (a2 + a3);
    } else if (isA2) {
      XDOT(68, w0); XDOT(72, w1); XDOT(76, w2); XDOT(80, w3);
      XDOT(84, w4); XDOT(88, w5); XDOT(92, w6); XDOT(96, w7);
      pbuf[600 + k0] = (a0 + a1) + (a2 + a3);
    }
    BAR();
    if (isA0) {
      float s = pbuf[tid] + pbuf[300 + tid] + pbuf[600 + tid] + bx;
      xproj[((size_t)c * 256 + t) * 300 + tid] = s;
    }
    BAR();
  }
#undef XDOT
}

// Stage one 16-step group (4800 floats = 1200 x 16B) of xproj into LDS.
// 512-thread version. LDS dest: wave-uniform base + lane*16B.
__device__ __forceinline__ void stage_chunk512(const float* __restrict__ gsrc,
                                               float* lds_dst, int tid) {
  int wave = tid >> 6;
#pragma unroll
  for (int r = 0; r < 2; r++) {
    const float* g = gsrc + (size_t)(r * 512 + tid) * 4;
    float* l = lds_dst + (r * 512 + wave * 64) * 4;
    __builtin_amdgcn_global_load_lds(
        (const __attribute__((address_space(1))) unsigned int*)g,
        (__attribute__((address_space(3))) unsigned int*)l, 16, 0, 0);
  }
  if (tid < 176) {
    const float* g = gsrc + (size_t)(1024 + tid) * 4;
    float* l = lds_dst + (1024 + wave * 64) * 4;
    __builtin_amdgcn_global_load_lds(
        (const __attribute__((address_space(1))) unsigned int*)g,
        (__attribute__((address_space(3))) unsigned int*)l, 16, 0, 0);
  }
}

// ---------------- GRU: chunked-parallel over t. Grid (16 c, 16 chunks).
// Round-6 512-thread structure, warm-up 32 (r9: absmax bit-identical).
__global__ __launch_bounds__(512, 2) void gru_kernel(
    const float* __restrict__ xproj, const float* __restrict__ wh,
    const float* __restrict__ gb, float* __restrict__ rnn) {
  int c = blockIdx.x;
  int chunk = blockIdx.y;
  int tid = threadIdx.x;
  __shared__ __align__(16) float h_lds[100];
  __shared__ float pbuf[1560];                    // [g*3+gt][104]
  __shared__ __align__(16) float xbuf[2][4800];   // 38.4 KB
  const float* whc = wh + (size_t)c * 30000;
  bool mv = (tid < 500);
  int g  = mv ? tid / 100 : 0;
  int k0 = tid - g * 100;
  int db = 20 * g;
  float4 z0, z1, z2, z3, z4, r0, r1, r2, r3, r4, q0, q1, q2, q3, q4;
  if (mv) {
    LWQ(z0, whc, db + 0, 0);   LWQ(z1, whc, db + 4, 0);   LWQ(z2, whc, db + 8, 0);
    LWQ(z3, whc, db + 12, 0);  LWQ(z4, whc, db + 16, 0);
    LWQ(r0, whc, db + 0, 100); LWQ(r1, whc, db + 4, 100); LWQ(r2, whc, db + 8, 100);
    LWQ(r3, whc, db + 12, 100);LWQ(r4, whc, db + 16, 100);
    LWQ(q0, whc, db + 0, 200); LWQ(q1, whc, db + 4, 200); LWQ(q2, whc, db + 8, 200);
    LWQ(q3, whc, db + 12, 200);LWQ(q4, whc, db + 16, 200);
  }
  float bzb = 0.f, brb = 0.f, bhb = 0.f, hprev = 0.f;
  if (tid < 100) {
    bzb = gb[c * 600 + 300 + tid];
    brb = gb[c * 600 + 400 + tid];
    bhb = gb[c * 600 + 500 + tid];
    h_lds[tid] = 0.0f;
  }
  int t0 = chunk * 16;                     // first output step
  int t_start = (t0 >= 32) ? t0 - 32 : 0;  // warm-up start (W=32)
  int ng = (t0 + 16 - t_start) >> 4;       // 16-step groups: 1..3
  const float* xp = xproj + (size_t)c * 76800 + (size_t)t_start * 300;

  stage_chunk512(xp, xbuf[0], tid);
  asm volatile("s_waitcnt vmcnt(0)" ::: "memory");
  BAR();

  int pb0 = g * 312 + k0;    // pbuf base for this thread's 3 partials
  int cur = 0;
  for (int g16 = 0; g16 < ng; g16++) {
    if (g16 + 1 < ng) stage_chunk512(xp + (size_t)(g16 + 1) * 4800, xbuf[cur ^ 1], tid);
    int tb = t_start + g16 * 16;
    for (int s = 0; s < 16; s++) {
      if (mv) {
        float4 h0 = *(const float4*)&h_lds[db];
        float4 h1 = *(const float4*)&h_lds[db + 4];
        float4 h2 = *(const float4*)&h_lds[db + 8];
        float4 h3 = *(const float4*)&h_lds[db + 12];
        float4 h4 = *(const float4*)&h_lds[db + 16];
        float pz, pr, ph;
        DOT20(pz, z0, z1, z2, z3, z4);
        DOT20(pr, r0, r1, r2, r3, r4);
        DOT20(ph, q0, q1, q2, q3, q4);
        pbuf[pb0]       = pz;
        pbuf[pb0 + 104] = pr;
        pbuf[pb0 + 208] = ph;
      }
      BAR();
      if (tid < 100) {
        const float* xr_ = &xbuf[cur][s * 300];
        float rz = ((pbuf[tid]       + pbuf[312 + tid]) + (pbuf[624 + tid] + pbuf[936 + tid])) + pbuf[1248 + tid] + bzb;
        float rr = ((pbuf[104 + tid] + pbuf[416 + tid]) + (pbuf[728 + tid] + pbuf[1040 + tid])) + pbuf[1352 + tid] + brb;
        float rh = ((pbuf[208 + tid] + pbuf[520 + tid]) + (pbuf[832 + tid] + pbuf[1144 + tid])) + pbuf[1456 + tid] + bhb;
        float z = 1.0f / (1.0f + __expf(-(xr_[tid] + rz)));
        float r = 1.0f / (1.0f + __expf(-(xr_[100 + tid] + rr)));
        float e = __expf(2.0f * (xr_[200 + tid] + r * rh));
        float hh = 1.0f - 2.0f / (e + 1.0f);     // tanh
        float hn = z * hprev + (1.0f - z) * hh;
        hprev = hn;
        h_lds[tid] = hn;
        int t = tb + s;
        if (t >= t0)
          rnn[((size_t)t * 100 + tid) * 16 + c] = hn;
      }
      BAR();
    }
    // group boundary: next xbuf fully loaded (and stores drained)
    asm volatile("s_waitcnt vmcnt(0)" ::: "memory");
    BAR();
    cur ^= 1;
  }
}

// ---------------- deconv1: (256,10,10,16) -> (256,40,40,8), s4 k7, exact <=2x2 taps
__global__ __launch_bounds__(256) void deconv1_kernel(
    const float* __restrict__ rnn, const float* __restrict__ wt,
    const float* __restrict__ bias, const float* __restrict__ gamma,
    const float* __restrict__ beta, float* __restrict__ out) {
  __shared__ __align__(16) float w[6272];   // [ky][kx][ic16][oc8]
  __shared__ float bb[8], sc[8], bt[8];
  for (int i = threadIdx.x; i < 6272; i += 256) w[i] = wt[i];
  if (threadIdx.x < 8) {
    bb[threadIdx.x] = bias[threadIdx.x];
    sc[threadIdx.x] = gamma[threadIdx.x] * rsqrtf(1.001f);
    bt[threadIdx.x] = beta[threadIdx.x];
  }
  __syncthreads();
  int idx = blockIdx.x * 256 + threadIdx.x;     // n*1600 + oy*40 + ox
  int ox = idx % 40; int t2 = idx / 40; int oy = t2 % 40; int n = t2 / 40;
  float acc[8];
#pragma unroll
  for (int o = 0; o < 8; o++) acc[o] = bb[o];
  int kyA = (5 - oy) & 3;     // ky ≡ 5-oy (mod 4) → py = oy+ky-5 ≡ 0 (mod 4)
  int kxA = (5 - ox) & 3;
  const float* rb = rnn + (size_t)n * 1600;
#pragma unroll
  for (int ia = 0; ia < 2; ia++) {
    int ky = kyA + 4 * ia;
    int py = oy + ky - 5;
    if (ky > 6 || (unsigned)py >= 40u) continue;
    int iy = py >> 2;
#pragma unroll
    for (int ib = 0; ib < 2; ib++) {
      int kx = kxA + 4 * ib;
      int px = ox + kx - 5;
      if (kx > 6 || (unsigned)px >= 40u) continue;
      int ix = px >> 2;
      const float4* ip = (const float4*)(rb + (iy * 10 + ix) * 16);
      float4 v0 = ip[0], v1 = ip[1], v2 = ip[2], v3 = ip[3];
      const float* wp = &w[(ky * 7 + kx) * 128];
      float xv[16] = {v0.x, v0.y, v0.z, v0.w, v1.x, v1.y, v1.z, v1.w,
                      v2.x, v2.y, v2.z, v2.w, v3.x, v3.y, v3.z, v3.w};
#pragma unroll
      for (int ic = 0; ic < 16; ic++) {
        const float4* wq = (const float4*)&wp[ic * 8];
        float4 wA = wq[0], wB = wq[1];
        acc[0] += xv[ic] * wA.x; acc[1] += xv[ic] * wA.y;
        acc[2] += xv[ic] * wA.z; acc[3] += xv[ic] * wA.w;
        acc[4] += xv[ic] * wB.x; acc[5] += xv[ic] * wB.y;
        acc[6] += xv[ic] * wB.z; acc[7] += xv[ic] * wB.w;
      }
    }
  }
#pragma unroll
  for (int o = 0; o < 8; o++) { float a = lrelu(acc[o]); acc[o] = a * sc[o] + bt[o]; }
  float4* op = (float4*)(out + (size_t)idx * 8);
  op[0] = make_float4(acc[0], acc[1], acc[2], acc[3]);
  op[1] = make_float4(acc[4], acc[5], acc[6], acc[7]);
}

// ---------------- deconv2: (256,40,40,8) -> (256,160,160,2), s4 k7.
// 4x4-output-block, GLOBAL scalar weights (r12: fixed the spill — VGPR 100,
// WRITE exactly 51.2MB). r12's per-tap sched_barrier over-serialized
// (VALUBusy 42%, 56.7µs): each tap stalled on its own lgkmcnt wait. Now
// fence per PAIR of taps: 32 scalars in flight (8 s_load_dwordx4, inside
// SGPR budget), 64cyc FMA per latency window, hoist window still too small
// to spill VGPRs.
// Tap map verified on HW (r10-r12 all passed, absmax identical):
//   ky: 0->(Y-1,r1) 1->(Y-1,r0) 2->(Y,r3) 3->(Y,r2) 4->(Y,r1) 5->(Y,r0) 6->(Y+1,r3)
//   kx: same map for columns.
#define D2TAP(KY, KX, R, C, CU, CQ)                                   \
  do {                                                                \
    const float* wp_ = wt + ((KY) * 7 + (KX)) * 16;                   \
    float s0_ = CU.x * wp_[0] + CU.y * wp_[2] + CU.z * wp_[4] +       \
                CU.w * wp_[6] + CQ.x * wp_[8] + CQ.y * wp_[10] +      \
                CQ.z * wp_[12] + CQ.w * wp_[14];                      \
    float s1_ = CU.x * wp_[1] + CU.y * wp_[3] + CU.z * wp_[5] +       \
                CU.w * wp_[7] + CQ.x * wp_[9] + CQ.y * wp_[11] +      \
                CQ.z * wp_[13] + CQ.w * wp_[15];                      \
    acc[R][C][0] += s0_;                                              \
    acc[R][C][1] += s1_;                                              \
  } while (0)

#define D2FENCE() __builtin_amdgcn_sched_barrier(0)

// All 7 kx taps for one ky (literal KY, literal output row R), fenced per pair:
#define D2ROW(KY, R)                                                  \
  do {                                                                \
    D2TAP(KY, 0, R, 1, u0, q0);                                       \
    D2TAP(KY, 1, R, 0, u0, q0);                                       \
    D2FENCE();                                                        \
    D2TAP(KY, 2, R, 3, u1, q1);                                       \
    D2TAP(KY, 3, R, 2, u1, q1);                                       \
    D2FENCE();                                                        \
    D2TAP(KY, 4, R, 1, u1, q1);                                       \
    D2TAP(KY, 5, R, 0, u1, q1);                                       \
    D2FENCE();                                                        \
    D2TAP(KY, 6, R, 3, u2, q2);                                       \
    D2FENCE();                                                        \
  } while (0)

__global__ __launch_bounds__(256) void deconv2_kernel(
    const float* __restrict__ y1, const float* __restrict__ wt,
    const float* __restrict__ bias, const float* __restrict__ gs,
    float* __restrict__ out) {
  int idx = blockIdx.x * 256 + threadIdx.x;     // n*1600 + Y*40 + X
  int X = idx % 40; int t2 = idx / 40; int Y = t2 % 40; int n = t2 / 40;
  float b0 = bias[0], b1 = bias[1];
  float acc[4][4][2];    // literal indices only (rule #20)
#pragma unroll
  for (int r = 0; r < 4; r++)
#pragma unroll
    for (int c = 0; c < 4; c++) { acc[r][c][0] = b0; acc[r][c][1] = b1; }
  const float* yb = y1 + (size_t)n * (40 * 40 * 8);
  const float4 z4 = make_float4(0.f, 0.f, 0.f, 0.f);
  float4 u0, q0, u1, q1, u2, q2;

#define D2LOADROW(IY)                                                 \
  do {                                                                \
    u0 = z4; q0 = z4; u1 = z4; q1 = z4; u2 = z4; q2 = z4;             \
    if ((unsigned)(IY) < 40u) {                                       \
      const float* rp_ = yb + (IY) * 320;                             \
      if (X > 0) { const float4* p_ = (const float4*)(rp_ + (X - 1) * 8); \
                   u0 = p_[0]; q0 = p_[1]; }                          \
      { const float4* p_ = (const float4*)(rp_ + X * 8);              \
        u1 = p_[0]; q1 = p_[1]; }                                     \
      if (X < 39) { const float4* p_ = (const float4*)(rp_ + (X + 1) * 8); \
                    u2 = p_[0]; q2 = p_[1]; }                         \
    }                                                                 \
    __builtin_amdgcn_sched_barrier(0);                                \
  } while (0)

  // input row Y-1: ky 0,1
  D2LOADROW(Y - 1);
  D2ROW(0, 1);
  D2ROW(1, 0);
  // input row Y: ky 2,3,4,5
  D2LOADROW(Y);
  D2ROW(2, 3);
  D2ROW(3, 2);
  D2ROW(4, 1);
  D2ROW(5, 0);
  // input row Y+1: ky 6
  D2LOADROW(Y + 1);
  D2ROW(6, 3);

  float g = gs[0];
  size_t ob = ((size_t)n * 160 + 4 * Y) * 160 + 4 * X;   // pixel index
#pragma unroll
  for (int r = 0; r < 4; r++) {
    float4 s0 = make_float4(g * lrelu(acc[r][0][0]), g * lrelu(acc[r][0][1]),
                            g * lrelu(acc[r][1][0]), g * lrelu(acc[r][1][1]));
    float4 s1 = make_float4(g * lrelu(acc[r][2][0]), g * lrelu(acc[r][2][1]),
                            g * lrelu(acc[r][3][0]), g * lrelu(acc[r][3][1]));
    float4* op = (float4*)(out + (ob + (size_t)r * 160) * 2);
    op[0] = s0;
    op[1] = s1;
  }
#undef D2LOADROW
}

extern "C" void kernel_launch(void* const* d_in, const int* in_sizes, int n_in,
                              void* d_out, int out_size, void* d_ws, size_t ws_size,
                              hipStream_t stream) {
  const float* lo_res   = (const float*)d_in[0];
  const float* conv1_k  = (const float*)d_in[1];
  const float* conv1_b  = (const float*)d_in[2];
  const float* bn1_g    = (const float*)d_in[3];
  const float* bn1_b    = (const float*)d_in[4];
  const float* conv2_k  = (const float*)d_in[5];
  const float* conv2_b  = (const float*)d_in[6];
  const float* bn2_g    = (const float*)d_in[7];
  const float* bn2_b    = (const float*)d_in[8];
  const float* gru_wx   = (const float*)d_in[9];
  const float* gru_wh   = (const float*)d_in[10];
  const float* gru_b    = (const float*)d_in[11];
  const float* deconv1_k = (const float*)d_in[12];
  const float* deconv1_b = (const float*)d_in[13];
  const float* deconv2_k = (const float*)d_in[14];
  const float* deconv2_b = (const float*)d_in[15];
  const float* gscale   = (const float*)d_in[16];

  float* ws = (float*)d_ws;
  float* x1    = ws;                    // 3,276,800
  float* x2    = x1 + 3276800;          //   409,600
  float* xproj = x2 + 409600;           // 1,228,800
  float* rnn   = xproj + 1228800;       //   409,600
  float* y1    = rnn + 409600;          // 3,276,800

  conv1_kernel<<<1600, 256, 0, stream>>>(lo_res, conv1_k, conv1_b, bn1_g, bn1_b, x1);
  conv2_kernel<<<1600, 256, 0, stream>>>(x1, conv2_k, conv2_b, bn2_g, bn2_b, x2);
  xproj_kernel<<<dim3(16, 16), 1024, 0, stream>>>(x2, gru_wx, gru_b, xproj);
  gru_kernel<<<dim3(16, 16), 512, 0, stream>>>(xproj, gru_wh, gru_b, rnn);
  deconv1_kernel<<<1600, 256, 0, stream>>>(rnn, deconv1_k, deconv1_b, bn1_g, bn1_b, y1);
  deconv2_kernel<<<1600, 256, 0, stream>>>(y1, deconv2_k, deconv2_b, gscale, (float*)d_out);
}